// Round 9
// baseline (582.316 us; speedup 1.0000x reference)
//
#include <hip/hip_runtime.h>
#include <hip/hip_bf16.h>
#include <math.h>

#define B_   8
#define T_   12
#define NN   325
#define DD   256
#define HH   8
#define HD   32
#define FFD  1024
#define MTOK (B_*T_*NN)     // 31200 tokens
#define QKVD 768            // packed QKV row stride
#define ATT_SCALE 0.17677669529663687f   // 1/sqrt(32)
#define LN_EPS 1e-5f
#define NEG_BIG (-1e30f)

typedef __attribute__((ext_vector_type(8))) __bf16 bf16x8;
typedef __attribute__((ext_vector_type(4))) float  f32x4;
typedef __attribute__((ext_vector_type(4))) short  shortx4;
typedef __attribute__((ext_vector_type(8))) unsigned short ushortx8;

static __device__ inline float bf2f(unsigned short u) {
  union { float f; unsigned int i; } c; c.i = ((unsigned int)u) << 16; return c.f;
}

// 16x16x16 bf16 MFMA (ISA: v_mfma_f32_16x16x16_bf16; A/B = 4 bf16/lane)
#if __has_builtin(__builtin_amdgcn_mfma_f32_16x16x16bf16_1k)
#define MFMA16(a,b,c) __builtin_amdgcn_mfma_f32_16x16x16bf16_1k((a),(b),(c),0,0,0)
#else
static __device__ inline f32x4 mfma16_fn(shortx4 a, shortx4 b, f32x4 c) {
  f32x4 d;
  asm volatile("v_mfma_f32_16x16x16_bf16 %0, %1, %2, %3"
               : "=v"(d) : "v"(a), "v"(b), "v"(c));
  return d;
}
#define MFMA16(a,b,c) mfma16_fn((a),(b),(c))
#endif

// ---------------------------------------------------------------------------
// Direct-load bf16 MFMA GEMM, HIGH-OCCUPANCY variant: no LDS, no barriers,
// small accumulator (wave tile 64x32, acc 32 AGPR) -> ~6 waves/SIMD so TLP
// hides global-load latency (R8 diagnosis: 3 waves/SIMD was the bottleneck).
// Block tile 128x64 (4 waves, 2x2). C[M,N] = A[M,K]@Wt[N,K]^T + bias, bf16 out.
// N-fastest grid + bijective XCD swizzle. gelu=1: exact GELU before store.
// ---------------------------------------------------------------------------
__global__ __launch_bounds__(256, 6) void gemm_direct(
    const __hip_bfloat16* __restrict__ A,
    const __hip_bfloat16* __restrict__ Wt,
    const float* __restrict__ bias,
    __hip_bfloat16* __restrict__ Cb,
    int Mr, int Nr, int Kr, int gelu)
{
  const int NB  = Nr >> 6;            // 64-wide N tiles
  const int nwg = gridDim.x;
  const int orig = blockIdx.x;
  const int qq = nwg >> 3, rr = nwg & 7;
  const int xcd = orig & 7, off = orig >> 3;
  const int id = (xcd < rr ? xcd * (qq + 1) : rr * (qq + 1) + (xcd - rr) * qq) + off;
  const int n0 = (id % NB) * 64;      // N fastest: consecutive ids share A-panel
  const int m0 = (id / NB) * 128;

  const int tid  = threadIdx.x;
  const int w    = tid >> 6;
  const int lane = tid & 63;
  const int wr   = w >> 1, wc = w & 1;   // wave tile: rows wr*64, cols wc*32
  const int lr   = lane & 15, lg = lane >> 4;

  f32x4 acc[4][2] = {};   // 4 x 16-row frags, 2 x 16-col frags = 32 AGPR

  const __hip_bfloat16* ap[4];
  const __hip_bfloat16* bp[2];
  #pragma unroll
  for (int i = 0; i < 4; ++i) {
    int r = m0 + wr * 64 + i * 16 + lr;
    if (r >= Mr) r = Mr - 1;            // clamp: duplicate read, masked at store
    ap[i] = A + (size_t)r * Kr + lg * 8;
  }
  #pragma unroll
  for (int j = 0; j < 2; ++j) {
    int c = n0 + wc * 32 + j * 16 + lr; // Nr multiple of 64 always
    bp[j] = Wt + (size_t)c * Kr + lg * 8;
  }

  const int nk = Kr >> 5;
  #pragma unroll 2
  for (int k = 0; k < nk; ++k) {
    bf16x8 af[4], bfr[2];
    #pragma unroll
    for (int i = 0; i < 4; ++i) af[i]  = *(const bf16x8*)(ap[i] + k * 32);
    #pragma unroll
    for (int j = 0; j < 2; ++j) bfr[j] = *(const bf16x8*)(bp[j] + k * 32);
    #pragma unroll
    for (int i = 0; i < 4; ++i)
      #pragma unroll
      for (int j = 0; j < 2; ++j)
        acc[i][j] = __builtin_amdgcn_mfma_f32_16x16x32_bf16(af[i], bfr[j], acc[i][j], 0, 0, 0);
  }

  // epilogue: C/D layout col = lane&15, row = (lane>>4)*4 + q
  #pragma unroll
  for (int i = 0; i < 4; ++i) {
    int rowb = m0 + wr * 64 + i * 16 + lg * 4;
    #pragma unroll
    for (int j = 0; j < 2; ++j) {
      int col = n0 + wc * 32 + j * 16 + lr;
      float bv = bias[col];
      #pragma unroll
      for (int q = 0; q < 4; ++q) {
        int gm = rowb + q;
        if (gm >= Mr) continue;
        float c = acc[i][j][q] + bv;
        if (gelu) c = 0.5f * c * (1.f + erff(c * 0.70710678118654752f));
        Cb[(size_t)gm * Nr + col] = __float2bfloat16(c);
      }
    }
  }
}

// ---------------------------------------------------------------------------
// Weight transpose + convert: Wt[N][K] bf16 <- W[K][N] fp32.
// ---------------------------------------------------------------------------
__global__ __launch_bounds__(256) void wt_cvt(
    const float* __restrict__ W, __hip_bfloat16* __restrict__ Wt, int K, int N)
{
  __shared__ float t[32][33];
  const int n0 = blockIdx.x * 32, k0 = blockIdx.y * 32;
  const int tx = threadIdx.x & 31, ty = threadIdx.x >> 5;
  #pragma unroll
  for (int i = 0; i < 32; i += 8)
    t[ty + i][tx] = W[(size_t)(k0 + ty + i) * N + n0 + tx];
  __syncthreads();
  #pragma unroll
  for (int i = 0; i < 32; i += 8)
    Wt[(size_t)(n0 + ty + i) * K + k0 + tx] = __float2bfloat16(t[tx][ty + i]);
}

__global__ __launch_bounds__(256) void cvt_bf16(
    const float* __restrict__ x, __hip_bfloat16* __restrict__ y, int n4)
{
  int i = blockIdx.x * 256 + threadIdx.x;
  if (i >= n4) return;
  float4 v = reinterpret_cast<const float4*>(x)[i];
  union { shortx4 s; __hip_bfloat16 h[4]; } u;
  u.h[0] = __float2bfloat16(v.x); u.h[1] = __float2bfloat16(v.y);
  u.h[2] = __float2bfloat16(v.z); u.h[3] = __float2bfloat16(v.w);
  reinterpret_cast<shortx4*>(y)[i] = u.s;
}

// concat 3x256 fp32 biases -> 768
__global__ __launch_bounds__(256) void bias_cat3(
    const float* __restrict__ a, const float* __restrict__ b,
    const float* __restrict__ c, float* __restrict__ o)
{
  int i = blockIdx.x * 256 + threadIdx.x;
  if (i < 256) o[i] = a[i];
  else if (i < 512) o[i] = b[i - 256];
  else if (i < 768) o[i] = c[i - 512];
}

// ---------------------------------------------------------------------------
// Pack adjacency mask to bits: mb[l][w] bit b = (adj[l][w*32+b] != 0).
// ---------------------------------------------------------------------------
__global__ __launch_bounds__(256) void maskpack(
    const int* __restrict__ adj, unsigned int* __restrict__ mb)
{
  int idx = blockIdx.x * 256 + threadIdx.x;
  if (idx >= NN * 11) return;
  int l = idx / 11, w = idx % 11;
  unsigned int bits = 0;
  #pragma unroll 4
  for (int b = 0; b < 32; ++b) {
    int m = w * 32 + b;
    if (m < NN && adj[l * NN + m] != 0) bits |= (1u << b);
  }
  mb[idx] = bits;
}

// ---------------------------------------------------------------------------
// MFMA spatial attention over packed QKV [M][768]. One WG per (g, h).
// S^T = mfma_16x16x32(K, Q); C-layout == x16 B-layout -> P feeds PV in-register.
// ---------------------------------------------------------------------------
__global__ __launch_bounds__(256) void spatial_attn_mfma(
    const __hip_bfloat16* __restrict__ qkv,
    const unsigned int* __restrict__ mb,
    __hip_bfloat16* __restrict__ out)
{
  constexpr int KP = 40;    // K_lds pitch: 80B rows, 2-way banks (free)
  constexpr int VP = 340;   // V^T pitch: 680B rows, 2-way (free)
  __shared__ unsigned short Kl[336 * KP];
  __shared__ unsigned short Vt[32 * VP];

  const int g = blockIdx.x, h = blockIdx.y;
  const int tid = threadIdx.x;
  const int w = tid >> 6, lane = tid & 63;
  const int lq = lane & 15, lg = lane >> 4;

  const size_t baseQ = (size_t)g * NN * QKVD + (size_t)h * HD;
  const size_t baseK = baseQ + 256;
  const size_t baseV = baseQ + 512;

  for (int idx = tid; idx < 32 * (VP - NN); idx += 256) {
    int d = idx / (VP - NN), kk = NN + idx % (VP - NN);
    Vt[d * VP + kk] = 0;
  }
  for (int idx = tid; idx < NN * 4; idx += 256) {
    int row = idx >> 2, cc = (idx & 3) * 8;
    union { bf16x8 v; unsigned short u[8]; } kv, vv;
    kv.v = *(const bf16x8*)&qkv[baseK + (size_t)row * QKVD + cc];
    *(bf16x8*)&Kl[row * KP + cc] = kv.v;
    vv.v = *(const bf16x8*)&qkv[baseV + (size_t)row * QKVD + cc];
    #pragma unroll
    for (int j = 0; j < 8; ++j) Vt[(cc + j) * VP + row] = vv.u[j];
  }
  __syncthreads();

  for (int qt = w; qt < 21; qt += 4) {
    const int query = qt * 16 + lq;
    const int qc = query < NN ? query : NN - 1;
    const bf16x8 qf = *(const bf16x8*)&qkv[baseQ + (size_t)qc * QKVD + lg * 8];
    const unsigned int* mrow = &mb[qc * 11];

    f32x4 accL = {0.f, 0.f, 0.f, 0.f};
    f32x4 accH = {0.f, 0.f, 0.f, 0.f};
    float mrun = -INFINITY, lrun = 0.f;

    for (int t = 0; t < 21; ++t) {
      bf16x8 kf = *(const bf16x8*)&Kl[(t * 16 + lq) * KP + lg * 8];
      f32x4 st = __builtin_amdgcn_mfma_f32_16x16x32_bf16(
          kf, qf, (f32x4){0.f, 0.f, 0.f, 0.f}, 0, 0, 0);
      const unsigned int mw = mrow[t >> 1];
      const int kbase = t * 16 + lg * 4;
      const int bbase = (t & 1) * 16 + lg * 4;
      float s[4];
      #pragma unroll
      for (int q = 0; q < 4; ++q) {
        float fill = (kbase + q < NN) ? NEG_BIG : -INFINITY;
        s[q] = ((mw >> (bbase + q)) & 1u) ? st[q] * ATT_SCALE : fill;
      }
      float tmax = fmaxf(fmaxf(s[0], s[1]), fmaxf(s[2], s[3]));
      tmax = fmaxf(tmax, __shfl_xor(tmax, 16));
      tmax = fmaxf(tmax, __shfl_xor(tmax, 32));
      const float mnew = fmaxf(mrun, tmax);
      const float corr = __expf(mrun - mnew);
      float p0 = __expf(s[0] - mnew), p1 = __expf(s[1] - mnew);
      float p2 = __expf(s[2] - mnew), p3 = __expf(s[3] - mnew);
      float ps = p0 + p1 + p2 + p3;
      ps += __shfl_xor(ps, 16);
      ps += __shfl_xor(ps, 32);
      lrun = lrun * corr + ps;
      mrun = mnew;
      accL *= corr; accH *= corr;
      union { shortx4 s4; __hip_bfloat16 hh[4]; } up;
      up.hh[0] = __float2bfloat16(p0); up.hh[1] = __float2bfloat16(p1);
      up.hh[2] = __float2bfloat16(p2); up.hh[3] = __float2bfloat16(p3);
      shortx4 vaL = *(const shortx4*)&Vt[lq * VP + kbase];
      shortx4 vaH = *(const shortx4*)&Vt[(lq + 16) * VP + kbase];
      accL = MFMA16(vaL, up.s4, accL);
      accH = MFMA16(vaH, up.s4, accH);
    }

    if (query < NN) {
      const float inv = 1.f / lrun;
      const size_t ob = ((size_t)(g * NN + query)) * DD + (size_t)h * HD;
      union { shortx4 s4; __hip_bfloat16 hh[4]; } uL, uH;
      #pragma unroll
      for (int q = 0; q < 4; ++q) {
        uL.hh[q] = __float2bfloat16(accL[q] * inv);
        uH.hh[q] = __float2bfloat16(accH[q] * inv);
      }
      *(shortx4*)&out[ob + lg * 4]      = uL.s4;
      *(shortx4*)&out[ob + 16 + lg * 4] = uH.s4;
    }
  }
}

// ---------------------------------------------------------------------------
// Temporal attention (causal, T=12) over packed bf16 QKV [M][768].
// ---------------------------------------------------------------------------
__global__ __launch_bounds__(256) void temporal_attn(
    const __hip_bfloat16* __restrict__ qkv, __hip_bfloat16* __restrict__ out)
{
  int idx = blockIdx.x * 256 + threadIdx.x;
  const int total = B_ * NN * HH * T_;
  if (idx >= total) return;

  int t  = idx % T_;
  int h  = (idx / T_) % HH;
  int n  = (idx / (T_ * HH)) % NN;
  int b  = idx / (T_ * HH * NN);

  const size_t tq = (size_t)((b * T_ + t) * NN + n) * QKVD + h * HD;
  float qr[HD];
  #pragma unroll
  for (int c8 = 0; c8 < 4; ++c8) {
    ushortx8 u = *(const ushortx8*)&qkv[tq + c8 * 8];
    #pragma unroll
    for (int j = 0; j < 8; ++j) qr[c8 * 8 + j] = bf2f(u[j]);
  }

  float o[HD] = {};
  float mrun = -INFINITY, lrun = 0.f;

  for (int tt = 0; tt <= t; ++tt) {
    const size_t tk = (size_t)((b * T_ + tt) * NN + n) * QKVD + h * HD;
    float s = 0.f;
    #pragma unroll
    for (int c8 = 0; c8 < 4; ++c8) {
      ushortx8 u = *(const ushortx8*)&qkv[tk + 256 + c8 * 8];
      #pragma unroll
      for (int j = 0; j < 8; ++j) s += qr[c8 * 8 + j] * bf2f(u[j]);
    }
    s *= ATT_SCALE;

    float mnew = fmaxf(mrun, s);
    float corr = __expf(mrun - mnew);
    float p = __expf(s - mnew);
    lrun = lrun * corr + p;
    #pragma unroll
    for (int c8 = 0; c8 < 4; ++c8) {
      ushortx8 u = *(const ushortx8*)&qkv[tk + 512 + c8 * 8];
      #pragma unroll
      for (int j = 0; j < 8; ++j) o[c8 * 8 + j] = o[c8 * 8 + j] * corr + p * bf2f(u[j]);
    }
    mrun = mnew;
  }

  float inv = 1.f / lrun;
  __hip_bfloat16* op = out + ((size_t)((b * T_ + t) * NN + n)) * DD + h * HD;
  #pragma unroll
  for (int d0 = 0; d0 < HD; d0 += 4) {
    union { shortx4 s; __hip_bfloat16 h4[4]; } u;
    #pragma unroll
    for (int j = 0; j < 4; ++j) u.h4[j] = __float2bfloat16(o[d0 + j] * inv);
    *reinterpret_cast<shortx4*>(op + d0) = u.s;
  }
}

// ---------------------------------------------------------------------------
// Fused residual-add + LayerNorm; x fp32, r bf16. fp32 out + optional bf16.
// ---------------------------------------------------------------------------
__global__ __launch_bounds__(64) void add_ln(
    const float* __restrict__ x, const __hip_bfloat16* __restrict__ r,
    const float* __restrict__ w, const float* __restrict__ bb,
    float* __restrict__ y, __hip_bfloat16* __restrict__ ybf)
{
  const size_t row = blockIdx.x;
  const int lane = threadIdx.x;

  const float4 xv = reinterpret_cast<const float4*>(x + row * DD)[lane];
  union { shortx4 s4; unsigned short u[4]; } rv;
  rv.s4 = reinterpret_cast<const shortx4*>(r + row * DD)[lane];
  float e[4] = {xv.x + bf2f(rv.u[0]), xv.y + bf2f(rv.u[1]),
                xv.z + bf2f(rv.u[2]), xv.w + bf2f(rv.u[3])};

  float s  = e[0] + e[1] + e[2] + e[3];
  float ss = e[0]*e[0] + e[1]*e[1] + e[2]*e[2] + e[3]*e[3];
  #pragma unroll
  for (int off = 32; off > 0; off >>= 1) {
    s  += __shfl_xor(s,  off, 64);
    ss += __shfl_xor(ss, off, 64);
  }
  float mu  = s * (1.f / DD);
  float var = ss * (1.f / DD) - mu * mu;
  float rs  = rsqrtf(var + LN_EPS);

  const float4 wv = reinterpret_cast<const float4*>(w)[lane];
  const float4 bv = reinterpret_cast<const float4*>(bb)[lane];
  float o0 = (e[0] - mu) * rs * wv.x + bv.x;
  float o1 = (e[1] - mu) * rs * wv.y + bv.y;
  float o2 = (e[2] - mu) * rs * wv.z + bv.z;
  float o3 = (e[3] - mu) * rs * wv.w + bv.w;
  float4 yv = {o0, o1, o2, o3};
  reinterpret_cast<float4*>(y + row * DD)[lane] = yv;
  if (ybf) {
    union { shortx4 s4; __hip_bfloat16 h4[4]; } u;
    u.h4[0] = __float2bfloat16(o0); u.h4[1] = __float2bfloat16(o1);
    u.h4[2] = __float2bfloat16(o2); u.h4[3] = __float2bfloat16(o3);
    reinterpret_cast<shortx4*>(ybf + row * DD)[lane] = u.s4;
  }
}

// ---------------------------------------------------------------------------
extern "C" void kernel_launch(void* const* d_in, const int* in_sizes, int n_in,
                              void* d_out, int out_size, void* d_ws, size_t ws_size,
                              hipStream_t stream)
{
  const float* x0   = (const float*)d_in[0];
  const int*   adj  = (const int*)  d_in[1];
  const float* sa_wq = (const float*)d_in[2];
  const float* sa_bq = (const float*)d_in[3];
  const float* sa_wk = (const float*)d_in[4];
  const float* sa_bk = (const float*)d_in[5];
  const float* sa_wv = (const float*)d_in[6];
  const float* sa_bv = (const float*)d_in[7];
  const float* sa_wo = (const float*)d_in[8];
  const float* sa_bo = (const float*)d_in[9];
  const float* sa_lw = (const float*)d_in[10];
  const float* sa_lb = (const float*)d_in[11];
  const float* ta_wq = (const float*)d_in[12];
  const float* ta_bq = (const float*)d_in[13];
  const float* ta_wk = (const float*)d_in[14];
  const float* ta_bk = (const float*)d_in[15];
  const float* ta_wv = (const float*)d_in[16];
  const float* ta_bv = (const float*)d_in[17];
  const float* ta_wo = (const float*)d_in[18];
  const float* ta_bo = (const float*)d_in[19];
  const float* ta_lw = (const float*)d_in[20];
  const float* ta_lb = (const float*)d_in[21];
  const float* f_w1  = (const float*)d_in[22];
  const float* f_b1  = (const float*)d_in[23];
  const float* f_w2  = (const float*)d_in[24];
  const float* f_b2  = (const float*)d_in[25];
  const float* f_lw  = (const float*)d_in[26];
  const float* f_lb  = (const float*)d_in[27];

  float* out = (float*)d_out;
  float* ws  = (float*)d_ws;

  const size_t P = (size_t)MTOK * DD;           // 7,987,200 floats (32 MB)
  if (ws_size < 7 * P * sizeof(float)) return;

  float* R0 = ws;                                 // x2 fp32 [0,1P)
  __hip_bfloat16* QKVb = (__hip_bfloat16*)(ws + P);     // [M,768] bf16 [1P,2.5P)
  __hip_bfloat16* HIDb = (__hip_bfloat16*)(ws + P);     // [M,1024] bf16, stage C [1P,3P)
  __hip_bfloat16* PRJ  = (__hip_bfloat16*)(ws + 3 * P); // proj out bf16 [3P,3.5P)
  float* R4 = ws + 4 * P;                         // x1 fp32 [4P,5P)
  __hip_bfloat16* X0b  = (__hip_bfloat16*)(ws + 5 * P);          // [5P,5.5P)
  __hip_bfloat16* X1b  = (__hip_bfloat16*)(ws + 5 * P + P / 2);  // [5.5P,6P)
  __hip_bfloat16* ATTb = (__hip_bfloat16*)(ws + 6 * P);          // [6P,6.5P)
  __hip_bfloat16* Wb   = (__hip_bfloat16*)(ws + 6 * P + P / 2);  // weights

  __hip_bfloat16* sa_qkv_t = Wb;                 // [768][256]
  __hip_bfloat16* ta_qkv_t = Wb + 196608;        // [768][256]
  __hip_bfloat16* sa_wo_t  = Wb + 393216;        // [256][256]
  __hip_bfloat16* ta_wo_t  = Wb + 458752;
  __hip_bfloat16* f_w1_t   = Wb + 524288;        // [1024][256]
  __hip_bfloat16* f_w2_t   = Wb + 786432;        // [256][1024]
  float* sa_qkvb = (float*)(Wb + 1048576);       // [768]
  float* ta_qkvb = sa_qkvb + 768;                // [768]
  unsigned int* MB = (unsigned int*)(ta_qkvb + 768);   // 325*11

  // ---- prep ----
  wt_cvt<<<dim3(DD/32, DD/32), 256, 0, stream>>>(sa_wq, sa_qkv_t,          DD, DD);
  wt_cvt<<<dim3(DD/32, DD/32), 256, 0, stream>>>(sa_wk, sa_qkv_t + 65536,  DD, DD);
  wt_cvt<<<dim3(DD/32, DD/32), 256, 0, stream>>>(sa_wv, sa_qkv_t + 131072, DD, DD);
  wt_cvt<<<dim3(DD/32, DD/32), 256, 0, stream>>>(ta_wq, ta_qkv_t,          DD, DD);
  wt_cvt<<<dim3(DD/32, DD/32), 256, 0, stream>>>(ta_wk, ta_qkv_t + 65536,  DD, DD);
  wt_cvt<<<dim3(DD/32, DD/32), 256, 0, stream>>>(ta_wv, ta_qkv_t + 131072, DD, DD);
  wt_cvt<<<dim3(DD/32, DD/32), 256, 0, stream>>>(sa_wo, sa_wo_t, DD, DD);
  wt_cvt<<<dim3(DD/32, DD/32), 256, 0, stream>>>(ta_wo, ta_wo_t, DD, DD);
  wt_cvt<<<dim3(FFD/32, DD/32), 256, 0, stream>>>(f_w1, f_w1_t, DD, FFD);
  wt_cvt<<<dim3(DD/32, FFD/32), 256, 0, stream>>>(f_w2, f_w2_t, FFD, DD);
  bias_cat3<<<3, 256, 0, stream>>>(sa_bq, sa_bk, sa_bv, sa_qkvb);
  bias_cat3<<<3, 256, 0, stream>>>(ta_bq, ta_bk, ta_bv, ta_qkvb);
  maskpack<<<(NN * 11 + 255) / 256, 256, 0, stream>>>(adj, MB);
  {
    int n4 = (int)(P / 4);
    cvt_bf16<<<(n4 + 255) / 256, 256, 0, stream>>>(x0, X0b, n4);
  }

  const int MBk = (MTOK + 127) / 128;   // 244
  auto gemm = [&](const __hip_bfloat16* A, const __hip_bfloat16* Wt, const float* bias,
                  __hip_bfloat16* Cb, int Nr, int Kr, int gelu) {
    int nwg = (Nr / 64) * MBk;
    gemm_direct<<<nwg, 256, 0, stream>>>(A, Wt, bias, Cb, MTOK, Nr, Kr, gelu);
  };

  // ---- Stage A: spatial attention ----
  gemm(X0b, sa_qkv_t, sa_qkvb, QKVb, QKVD, DD, 0);
  spatial_attn_mfma<<<dim3(B_ * T_, HH), 256, 0, stream>>>(QKVb, MB, ATTb);
  gemm(ATTb, sa_wo_t, sa_bo, PRJ, DD, DD, 0);
  add_ln<<<MTOK, 64, 0, stream>>>(x0, PRJ, sa_lw, sa_lb, R4, X1b);   // x1: R4 + X1b

  // ---- Stage B: temporal attention ----
  gemm(X1b, ta_qkv_t, ta_qkvb, QKVb, QKVD, DD, 0);
  {
    int total = B_ * NN * HH * T_;
    temporal_attn<<<(total + 255) / 256, 256, 0, stream>>>(QKVb, ATTb);
  }
  gemm(ATTb, ta_wo_t, ta_bo, PRJ, DD, DD, 0);
  add_ln<<<MTOK, 64, 0, stream>>>(R4, PRJ, ta_lw, ta_lb, R0, X0b);   // x2: R0 + X0b

  // ---- Stage C: FFN ----
  gemm(X0b, f_w1_t, f_b1, HIDb, FFD, DD, 1);                         // GELU, bf16 hidden
  gemm(HIDb, f_w2_t, f_b2, PRJ, DD, FFD, 0);
  add_ln<<<MTOK, 64, 0, stream>>>(R0, PRJ, f_lw, f_lb, out, nullptr);
}

// Round 10
// 456.706 us; speedup vs baseline: 1.2750x; 1.2750x over previous
//
#include <hip/hip_runtime.h>
#include <hip/hip_bf16.h>
#include <math.h>

#define B_   8
#define T_   12
#define NN   325
#define DD   256
#define HH   8
#define HD   32
#define FFD  1024
#define MTOK (B_*T_*NN)     // 31200 tokens
#define QKVD 768            // packed QKV row stride
#define ATT_SCALE 0.17677669529663687f   // 1/sqrt(32)
#define LN_EPS 1e-5f
#define NEG_BIG (-1e30f)

typedef __attribute__((ext_vector_type(8))) __bf16 bf16x8;
typedef __attribute__((ext_vector_type(4))) float  f32x4;
typedef __attribute__((ext_vector_type(4))) short  shortx4;
typedef __attribute__((ext_vector_type(8))) unsigned short ushortx8;

static __device__ inline float bf2f(unsigned short u) {
  union { float f; unsigned int i; } c; c.i = ((unsigned int)u) << 16; return c.f;
}

#if __has_builtin(__builtin_amdgcn_mfma_f32_16x16x16bf16_1k)
#define MFMA16(a,b,c) __builtin_amdgcn_mfma_f32_16x16x16bf16_1k((a),(b),(c),0,0,0)
#else
static __device__ inline f32x4 mfma16_fn(shortx4 a, shortx4 b, f32x4 c) {
  f32x4 d;
  asm volatile("v_mfma_f32_16x16x16_bf16 %0, %1, %2, %3"
               : "=v"(d) : "v"(a), "v"(b), "v"(c));
  return d;
}
#define MFMA16(a,b,c) mfma16_fn((a),(b),(c))
#endif

// async global->LDS, 16B per lane, wave-uniform LDS base + lane*16
#define GLDS(gsrc, ldst) \
  __builtin_amdgcn_global_load_lds((const __attribute__((address_space(1))) void*)(gsrc), \
                                   (__attribute__((address_space(3))) void*)(ldst), 16, 0, 0)

// ---------------------------------------------------------------------------
// Persistent-B barrier-free GEMM for K=256 (QKV, WO, FFN1).
// B-slice [64 x 256] staged ONCE to LDS (pitch 264 -> 2-way banks, free);
// then 4 m-tiles x 8 k-steps of {4 A global loads, 2 B ds_reads, 8 MFMA}
// with ZERO barriers in the loop -> compiler pipelines loads over MFMAs
// arbitrarily deep (the pattern that made spatial_attn fast).
// Block: 4 waves 2x2, wave tile 64x32, acc[4][2]=32 AGPR.
// ---------------------------------------------------------------------------
__global__ __launch_bounds__(256) void gemm_persist(
    const __hip_bfloat16* __restrict__ A,
    const __hip_bfloat16* __restrict__ Wt,
    const float* __restrict__ bias,
    __hip_bfloat16* __restrict__ Cb,
    int Mr, int Nr, int gelu)
{
  constexpr int KR = 256;
  constexpr int BP = 264;                  // LDS pitch (bf16): 528B rows
  __shared__ __hip_bfloat16 Bs[64 * BP];   // 33.8 KB

  const int NS  = Nr >> 6;
  const int nwg = gridDim.x;
  const int orig = blockIdx.x;
  const int qq = nwg >> 3, rr = nwg & 7;
  const int xcd = orig & 7, off = orig >> 3;
  const int id = (xcd < rr ? xcd * (qq + 1) : rr * (qq + 1) + (xcd - rr) * qq) + off;
  const int n0 = (id % NS) * 64;           // N fastest: consecutive ids share A
  const int mg = id / NS;                  // m-group: 4 m-tiles of 128 rows

  const int tid = threadIdx.x;
  const int w = tid >> 6, lane = tid & 63;
  const int wr = w >> 1, wc = w & 1;
  const int lr = lane & 15, lg = lane >> 4;

  // stage B-slice once (plain loads; one-time cost)
  for (int u = tid; u < 64 * 32; u += 256) {
    int row = u >> 5, c8 = (u & 31) * 8;
    bf16x8 v = *(const bf16x8*)&Wt[(size_t)(n0 + row) * KR + c8];
    *(bf16x8*)&Bs[row * BP + c8] = v;
  }
  __syncthreads();                         // the ONLY barrier in this kernel

  int offB[2];
  #pragma unroll
  for (int j = 0; j < 2; ++j) offB[j] = (wc * 32 + j * 16 + lr) * BP;

  float bv[2];
  #pragma unroll
  for (int j = 0; j < 2; ++j) bv[j] = bias[n0 + wc * 32 + j * 16 + lr];

  #pragma unroll 1
  for (int mt = 0; mt < 4; ++mt) {
    const int mbase = (mg * 4 + mt) * 128;
    const __hip_bfloat16* ap[4];
    #pragma unroll
    for (int i = 0; i < 4; ++i) {
      int r = mbase + wr * 64 + i * 16 + lr;
      if (r >= Mr) r = Mr - 1;             // clamp; store masked below
      ap[i] = A + (size_t)r * KR + lg * 8;
    }

    f32x4 acc[4][2] = {};
    #pragma unroll
    for (int k = 0; k < 8; ++k) {
      bf16x8 af[4], bfr[2];
      #pragma unroll
      for (int i = 0; i < 4; ++i) af[i] = *(const bf16x8*)(ap[i] + k * 32);
      #pragma unroll
      for (int j = 0; j < 2; ++j)
        bfr[j] = *(const bf16x8*)&Bs[offB[j] + k * 32 + lg * 8];
      #pragma unroll
      for (int i = 0; i < 4; ++i)
        #pragma unroll
        for (int j = 0; j < 2; ++j)
          acc[i][j] = __builtin_amdgcn_mfma_f32_16x16x32_bf16(af[i], bfr[j], acc[i][j], 0, 0, 0);
    }

    // epilogue: col = lane&15, row = lg*4 + q
    #pragma unroll
    for (int i = 0; i < 4; ++i) {
      int rowb = mbase + wr * 64 + i * 16 + lg * 4;
      #pragma unroll
      for (int j = 0; j < 2; ++j) {
        int col = n0 + wc * 32 + j * 16 + lr;
        #pragma unroll
        for (int q = 0; q < 4; ++q) {
          int gm = rowb + q;
          if (gm >= Mr) continue;
          float c = acc[i][j][q] + bv[j];
          if (gelu) c = 0.5f * c * (1.f + erff(c * 0.70710678118654752f));
          Cb[(size_t)gm * Nr + col] = __float2bfloat16(c);
        }
      }
    }
  }
}

// ---------------------------------------------------------------------------
// K=1024 GEMM (FFN2 only): R7-validated counted-vmcnt pipeline + swizzled LDS.
// 128x128 tile, BK=32, 4 waves, bf16 out.
// ---------------------------------------------------------------------------
__global__ __launch_bounds__(256) void gemm_k1024(
    const __hip_bfloat16* __restrict__ A,
    const __hip_bfloat16* __restrict__ Wt,
    const float* __restrict__ bias,
    __hip_bfloat16* __restrict__ Cb,
    int Mr, int Nr, int Kr)
{
  __shared__ __hip_bfloat16 As[2][128 * 32];
  __shared__ __hip_bfloat16 Bs[2][128 * 32];

  const int NB  = Nr >> 7;
  const int nwg = gridDim.x;
  const int orig = blockIdx.x;
  const int qq = nwg >> 3, rr = nwg & 7;
  const int xcd = orig & 7, off = orig >> 3;
  const int id = (xcd < rr ? xcd * (qq + 1) : rr * (qq + 1) + (xcd - rr) * qq) + off;
  const int n0 = (id % NB) * 128;
  const int m0 = (id / NB) * 128;

  const int tid  = threadIdx.x;
  const int w    = tid >> 6;
  const int lane = tid & 63;
  const int wr   = w >> 1, wc = w & 1;

  f32x4 acc[4][4] = {};

  const int c4   = lane & 3;
  const int r0   = w * 32 + (lane >> 2);
  const int csw  = (c4 - (r0 >> 1)) & 3;
  const int scol = csw * 8;
  int ar0 = m0 + r0;      if (ar0 >= Mr) ar0 = Mr - 1;
  int ar1 = m0 + r0 + 16; if (ar1 >= Mr) ar1 = Mr - 1;
  const size_t aOff0 = (size_t)ar0 * Kr + scol;
  const size_t aOff1 = (size_t)ar1 * Kr + scol;
  const size_t bOff0 = (size_t)(n0 + r0) * Kr + scol;
  const size_t bOff1 = (size_t)(n0 + r0 + 16) * Kr + scol;

  const int lr = lane & 15;
  const int lg = lane >> 4;
  int offA[4], offB[4];
  #pragma unroll
  for (int i = 0; i < 4; ++i) {
    int rA = wr * 64 + i * 16 + lr;
    offA[i] = rA * 32 + (((lg + (rA >> 1)) & 3) * 8);
    int rB = wc * 64 + i * 16 + lr;
    offB[i] = rB * 32 + (((lg + (rB >> 1)) & 3) * 8);
  }
  const int nk = Kr >> 5;

#define STAGE_T(buf, k0) do { \
    GLDS(&A[aOff0 + (k0)],  &As[buf][(w * 32) * 32]); \
    GLDS(&A[aOff1 + (k0)],  &As[buf][(w * 32 + 16) * 32]); \
    GLDS(&Wt[bOff0 + (k0)], &Bs[buf][(w * 32) * 32]); \
    GLDS(&Wt[bOff1 + (k0)], &Bs[buf][(w * 32 + 16) * 32]); \
  } while (0)

  STAGE_T(0, 0);
  if (nk > 1) STAGE_T(1, 32);

  for (int k = 0; k < nk; ++k) {
    if (k + 1 < nk) asm volatile("s_waitcnt vmcnt(4)" ::: "memory");
    else            asm volatile("s_waitcnt vmcnt(0)" ::: "memory");
    __builtin_amdgcn_s_barrier();

    const int buf = k & 1;
    bf16x8 af[4], bfr[4];
    #pragma unroll
    for (int i = 0; i < 4; ++i) {
      af[i]  = *(const bf16x8*)&As[buf][offA[i]];
      bfr[i] = *(const bf16x8*)&Bs[buf][offB[i]];
    }
    asm volatile("s_waitcnt lgkmcnt(0)" ::: "memory");
    __builtin_amdgcn_sched_barrier(0);
    __builtin_amdgcn_s_barrier();

    if (k + 2 < nk) STAGE_T(buf, (k + 2) * 32);

    #pragma unroll
    for (int i = 0; i < 4; ++i)
      #pragma unroll
      for (int j = 0; j < 4; ++j)
        acc[i][j] = __builtin_amdgcn_mfma_f32_16x16x32_bf16(af[i], bfr[j], acc[i][j], 0, 0, 0);
  }
#undef STAGE_T

  #pragma unroll
  for (int i = 0; i < 4; ++i) {
    int rowb = m0 + wr * 64 + i * 16 + lg * 4;
    #pragma unroll
    for (int j = 0; j < 4; ++j) {
      int col = n0 + wc * 64 + j * 16 + lr;
      float bv = bias[col];
      #pragma unroll
      for (int q = 0; q < 4; ++q) {
        int gm = rowb + q;
        if (gm >= Mr) continue;
        Cb[(size_t)gm * Nr + col] = __float2bfloat16(acc[i][j][q] + bv);
      }
    }
  }
}

// ---------------------------------------------------------------------------
__global__ __launch_bounds__(256) void wt_cvt(
    const float* __restrict__ W, __hip_bfloat16* __restrict__ Wt, int K, int N)
{
  __shared__ float t[32][33];
  const int n0 = blockIdx.x * 32, k0 = blockIdx.y * 32;
  const int tx = threadIdx.x & 31, ty = threadIdx.x >> 5;
  #pragma unroll
  for (int i = 0; i < 32; i += 8)
    t[ty + i][tx] = W[(size_t)(k0 + ty + i) * N + n0 + tx];
  __syncthreads();
  #pragma unroll
  for (int i = 0; i < 32; i += 8)
    Wt[(size_t)(n0 + ty + i) * K + k0 + tx] = __float2bfloat16(t[tx][ty + i]);
}

__global__ __launch_bounds__(256) void cvt_bf16(
    const float* __restrict__ x, __hip_bfloat16* __restrict__ y, int n4)
{
  int i = blockIdx.x * 256 + threadIdx.x;
  if (i >= n4) return;
  float4 v = reinterpret_cast<const float4*>(x)[i];
  union { shortx4 s; __hip_bfloat16 h[4]; } u;
  u.h[0] = __float2bfloat16(v.x); u.h[1] = __float2bfloat16(v.y);
  u.h[2] = __float2bfloat16(v.z); u.h[3] = __float2bfloat16(v.w);
  reinterpret_cast<shortx4*>(y)[i] = u.s;
}

__global__ __launch_bounds__(256) void bias_cat3(
    const float* __restrict__ a, const float* __restrict__ b,
    const float* __restrict__ c, float* __restrict__ o)
{
  int i = blockIdx.x * 256 + threadIdx.x;
  if (i < 256) o[i] = a[i];
  else if (i < 512) o[i] = b[i - 256];
  else if (i < 768) o[i] = c[i - 512];
}

__global__ __launch_bounds__(256) void maskpack(
    const int* __restrict__ adj, unsigned int* __restrict__ mb)
{
  int idx = blockIdx.x * 256 + threadIdx.x;
  if (idx >= NN * 11) return;
  int l = idx / 11, w = idx % 11;
  unsigned int bits = 0;
  #pragma unroll 4
  for (int b = 0; b < 32; ++b) {
    int m = w * 32 + b;
    if (m < NN && adj[l * NN + m] != 0) bits |= (1u << b);
  }
  mb[idx] = bits;
}

// ---------------------------------------------------------------------------
// MFMA spatial attention over packed QKV [M][768]. One WG per (g, h).
// ---------------------------------------------------------------------------
__global__ __launch_bounds__(256) void spatial_attn_mfma(
    const __hip_bfloat16* __restrict__ qkv,
    const unsigned int* __restrict__ mb,
    __hip_bfloat16* __restrict__ out)
{
  constexpr int KP = 40;
  constexpr int VP = 340;
  __shared__ unsigned short Kl[336 * KP];
  __shared__ unsigned short Vt[32 * VP];

  const int g = blockIdx.x, h = blockIdx.y;
  const int tid = threadIdx.x;
  const int w = tid >> 6, lane = tid & 63;
  const int lq = lane & 15, lg = lane >> 4;

  const size_t baseQ = (size_t)g * NN * QKVD + (size_t)h * HD;
  const size_t baseK = baseQ + 256;
  const size_t baseV = baseQ + 512;

  for (int idx = tid; idx < 32 * (VP - NN); idx += 256) {
    int d = idx / (VP - NN), kk = NN + idx % (VP - NN);
    Vt[d * VP + kk] = 0;
  }
  for (int idx = tid; idx < NN * 4; idx += 256) {
    int row = idx >> 2, cc = (idx & 3) * 8;
    union { bf16x8 v; unsigned short u[8]; } kv, vv;
    kv.v = *(const bf16x8*)&qkv[baseK + (size_t)row * QKVD + cc];
    *(bf16x8*)&Kl[row * KP + cc] = kv.v;
    vv.v = *(const bf16x8*)&qkv[baseV + (size_t)row * QKVD + cc];
    #pragma unroll
    for (int j = 0; j < 8; ++j) Vt[(cc + j) * VP + row] = vv.u[j];
  }
  __syncthreads();

  for (int qt = w; qt < 21; qt += 4) {
    const int query = qt * 16 + lq;
    const int qc = query < NN ? query : NN - 1;
    const bf16x8 qf = *(const bf16x8*)&qkv[baseQ + (size_t)qc * QKVD + lg * 8];
    const unsigned int* mrow = &mb[qc * 11];

    f32x4 accL = {0.f, 0.f, 0.f, 0.f};
    f32x4 accH = {0.f, 0.f, 0.f, 0.f};
    float mrun = -INFINITY, lrun = 0.f;

    for (int t = 0; t < 21; ++t) {
      bf16x8 kf = *(const bf16x8*)&Kl[(t * 16 + lq) * KP + lg * 8];
      f32x4 st = __builtin_amdgcn_mfma_f32_16x16x32_bf16(
          kf, qf, (f32x4){0.f, 0.f, 0.f, 0.f}, 0, 0, 0);
      const unsigned int mw = mrow[t >> 1];
      const int kbase = t * 16 + lg * 4;
      const int bbase = (t & 1) * 16 + lg * 4;
      float s[4];
      #pragma unroll
      for (int q = 0; q < 4; ++q) {
        float fill = (kbase + q < NN) ? NEG_BIG : -INFINITY;
        s[q] = ((mw >> (bbase + q)) & 1u) ? st[q] * ATT_SCALE : fill;
      }
      float tmax = fmaxf(fmaxf(s[0], s[1]), fmaxf(s[2], s[3]));
      tmax = fmaxf(tmax, __shfl_xor(tmax, 16));
      tmax = fmaxf(tmax, __shfl_xor(tmax, 32));
      const float mnew = fmaxf(mrun, tmax);
      const float corr = __expf(mrun - mnew);
      float p0 = __expf(s[0] - mnew), p1 = __expf(s[1] - mnew);
      float p2 = __expf(s[2] - mnew), p3 = __expf(s[3] - mnew);
      float ps = p0 + p1 + p2 + p3;
      ps += __shfl_xor(ps, 16);
      ps += __shfl_xor(ps, 32);
      lrun = lrun * corr + ps;
      mrun = mnew;
      accL *= corr; accH *= corr;
      union { shortx4 s4; __hip_bfloat16 hh[4]; } up;
      up.hh[0] = __float2bfloat16(p0); up.hh[1] = __float2bfloat16(p1);
      up.hh[2] = __float2bfloat16(p2); up.hh[3] = __float2bfloat16(p3);
      shortx4 vaL = *(const shortx4*)&Vt[lq * VP + kbase];
      shortx4 vaH = *(const shortx4*)&Vt[(lq + 16) * VP + kbase];
      accL = MFMA16(vaL, up.s4, accL);
      accH = MFMA16(vaH, up.s4, accH);
    }

    if (query < NN) {
      const float inv = 1.f / lrun;
      const size_t ob = ((size_t)(g * NN + query)) * DD + (size_t)h * HD;
      union { shortx4 s4; __hip_bfloat16 hh[4]; } uL, uH;
      #pragma unroll
      for (int q = 0; q < 4; ++q) {
        uL.hh[q] = __float2bfloat16(accL[q] * inv);
        uH.hh[q] = __float2bfloat16(accH[q] * inv);
      }
      *(shortx4*)&out[ob + lg * 4]      = uL.s4;
      *(shortx4*)&out[ob + 16 + lg * 4] = uH.s4;
    }
  }
}

// ---------------------------------------------------------------------------
__global__ __launch_bounds__(256) void temporal_attn(
    const __hip_bfloat16* __restrict__ qkv, __hip_bfloat16* __restrict__ out)
{
  int idx = blockIdx.x * 256 + threadIdx.x;
  const int total = B_ * NN * HH * T_;
  if (idx >= total) return;

  int t  = idx % T_;
  int h  = (idx / T_) % HH;
  int n  = (idx / (T_ * HH)) % NN;
  int b  = idx / (T_ * HH * NN);

  const size_t tq = (size_t)((b * T_ + t) * NN + n) * QKVD + h * HD;
  float qr[HD];
  #pragma unroll
  for (int c8 = 0; c8 < 4; ++c8) {
    ushortx8 u = *(const ushortx8*)&qkv[tq + c8 * 8];
    #pragma unroll
    for (int j = 0; j < 8; ++j) qr[c8 * 8 + j] = bf2f(u[j]);
  }

  float o[HD] = {};
  float mrun = -INFINITY, lrun = 0.f;

  for (int tt = 0; tt <= t; ++tt) {
    const size_t tk = (size_t)((b * T_ + tt) * NN + n) * QKVD + h * HD;
    float s = 0.f;
    #pragma unroll
    for (int c8 = 0; c8 < 4; ++c8) {
      ushortx8 u = *(const ushortx8*)&qkv[tk + 256 + c8 * 8];
      #pragma unroll
      for (int j = 0; j < 8; ++j) s += qr[c8 * 8 + j] * bf2f(u[j]);
    }
    s *= ATT_SCALE;

    float mnew = fmaxf(mrun, s);
    float corr = __expf(mrun - mnew);
    float p = __expf(s - mnew);
    lrun = lrun * corr + p;
    #pragma unroll
    for (int c8 = 0; c8 < 4; ++c8) {
      ushortx8 u = *(const ushortx8*)&qkv[tk + 512 + c8 * 8];
      #pragma unroll
      for (int j = 0; j < 8; ++j) o[c8 * 8 + j] = o[c8 * 8 + j] * corr + p * bf2f(u[j]);
    }
    mrun = mnew;
  }

  float inv = 1.f / lrun;
  __hip_bfloat16* op = out + ((size_t)((b * T_ + t) * NN + n)) * DD + h * HD;
  #pragma unroll
  for (int d0 = 0; d0 < HD; d0 += 4) {
    union { shortx4 s; __hip_bfloat16 h4[4]; } u;
    #pragma unroll
    for (int j = 0; j < 4; ++j) u.h4[j] = __float2bfloat16(o[d0 + j] * inv);
    *reinterpret_cast<shortx4*>(op + d0) = u.s;
  }
}

// ---------------------------------------------------------------------------
__global__ __launch_bounds__(64) void add_ln(
    const float* __restrict__ x, const __hip_bfloat16* __restrict__ r,
    const float* __restrict__ w, const float* __restrict__ bb,
    float* __restrict__ y, __hip_bfloat16* __restrict__ ybf)
{
  const size_t row = blockIdx.x;
  const int lane = threadIdx.x;

  const float4 xv = reinterpret_cast<const float4*>(x + row * DD)[lane];
  union { shortx4 s4; unsigned short u[4]; } rv;
  rv.s4 = reinterpret_cast<const shortx4*>(r + row * DD)[lane];
  float e[4] = {xv.x + bf2f(rv.u[0]), xv.y + bf2f(rv.u[1]),
                xv.z + bf2f(rv.u[2]), xv.w + bf2f(rv.u[3])};

  float s  = e[0] + e[1] + e[2] + e[3];
  float ss = e[0]*e[0] + e[1]*e[1] + e[2]*e[2] + e[3]*e[3];
  #pragma unroll
  for (int off = 32; off > 0; off >>= 1) {
    s  += __shfl_xor(s,  off, 64);
    ss += __shfl_xor(ss, off, 64);
  }
  float mu  = s * (1.f / DD);
  float var = ss * (1.f / DD) - mu * mu;
  float rs  = rsqrtf(var + LN_EPS);

  const float4 wv = reinterpret_cast<const float4*>(w)[lane];
  const float4 bv = reinterpret_cast<const float4*>(bb)[lane];
  float o0 = (e[0] - mu) * rs * wv.x + bv.x;
  float o1 = (e[1] - mu) * rs * wv.y + bv.y;
  float o2 = (e[2] - mu) * rs * wv.z + bv.z;
  float o3 = (e[3] - mu) * rs * wv.w + bv.w;
  float4 yv = {o0, o1, o2, o3};
  reinterpret_cast<float4*>(y + row * DD)[lane] = yv;
  if (ybf) {
    union { shortx4 s4; __hip_bfloat16 h4[4]; } u;
    u.h4[0] = __float2bfloat16(o0); u.h4[1] = __float2bfloat16(o1);
    u.h4[2] = __float2bfloat16(o2); u.h4[3] = __float2bfloat16(o3);
    reinterpret_cast<shortx4*>(ybf + row * DD)[lane] = u.s4;
  }
}

// ---------------------------------------------------------------------------
extern "C" void kernel_launch(void* const* d_in, const int* in_sizes, int n_in,
                              void* d_out, int out_size, void* d_ws, size_t ws_size,
                              hipStream_t stream)
{
  const float* x0   = (const float*)d_in[0];
  const int*   adj  = (const int*)  d_in[1];
  const float* sa_wq = (const float*)d_in[2];
  const float* sa_bq = (const float*)d_in[3];
  const float* sa_wk = (const float*)d_in[4];
  const float* sa_bk = (const float*)d_in[5];
  const float* sa_wv = (const float*)d_in[6];
  const float* sa_bv = (const float*)d_in[7];
  const float* sa_wo = (const float*)d_in[8];
  const float* sa_bo = (const float*)d_in[9];
  const float* sa_lw = (const float*)d_in[10];
  const float* sa_lb = (const float*)d_in[11];
  const float* ta_wq = (const float*)d_in[12];
  const float* ta_bq = (const float*)d_in[13];
  const float* ta_wk = (const float*)d_in[14];
  const float* ta_bk = (const float*)d_in[15];
  const float* ta_wv = (const float*)d_in[16];
  const float* ta_bv = (const float*)d_in[17];
  const float* ta_wo = (const float*)d_in[18];
  const float* ta_bo = (const float*)d_in[19];
  const float* ta_lw = (const float*)d_in[20];
  const float* ta_lb = (const float*)d_in[21];
  const float* f_w1  = (const float*)d_in[22];
  const float* f_b1  = (const float*)d_in[23];
  const float* f_w2  = (const float*)d_in[24];
  const float* f_b2  = (const float*)d_in[25];
  const float* f_lw  = (const float*)d_in[26];
  const float* f_lb  = (const float*)d_in[27];

  float* out = (float*)d_out;
  float* ws  = (float*)d_ws;

  const size_t P = (size_t)MTOK * DD;           // 7,987,200 floats (32 MB)
  if (ws_size < 7 * P * sizeof(float)) return;

  float* R0 = ws;                                 // x2 fp32 [0,1P)
  __hip_bfloat16* QKVb = (__hip_bfloat16*)(ws + P);     // [M,768] bf16 [1P,2.5P)
  __hip_bfloat16* HIDb = (__hip_bfloat16*)(ws + P);     // [M,1024] bf16, stage C [1P,3P)
  __hip_bfloat16* PRJ  = (__hip_bfloat16*)(ws + 3 * P); // proj out bf16 [3P,3.5P)
  float* R4 = ws + 4 * P;                         // x1 fp32 [4P,5P)
  __hip_bfloat16* X0b  = (__hip_bfloat16*)(ws + 5 * P);          // [5P,5.5P)
  __hip_bfloat16* X1b  = (__hip_bfloat16*)(ws + 5 * P + P / 2);  // [5.5P,6P)
  __hip_bfloat16* ATTb = (__hip_bfloat16*)(ws + 6 * P);          // [6P,6.5P)
  __hip_bfloat16* Wb   = (__hip_bfloat16*)(ws + 6 * P + P / 2);  // weights

  __hip_bfloat16* sa_qkv_t = Wb;                 // [768][256]
  __hip_bfloat16* ta_qkv_t = Wb + 196608;        // [768][256]
  __hip_bfloat16* sa_wo_t  = Wb + 393216;        // [256][256]
  __hip_bfloat16* ta_wo_t  = Wb + 458752;
  __hip_bfloat16* f_w1_t   = Wb + 524288;        // [1024][256]
  __hip_bfloat16* f_w2_t   = Wb + 786432;        // [256][1024]
  float* sa_qkvb = (float*)(Wb + 1048576);       // [768]
  float* ta_qkvb = sa_qkvb + 768;                // [768]
  unsigned int* MB = (unsigned int*)(ta_qkvb + 768);   // 325*11

  // ---- prep ----
  wt_cvt<<<dim3(DD/32, DD/32), 256, 0, stream>>>(sa_wq, sa_qkv_t,          DD, DD);
  wt_cvt<<<dim3(DD/32, DD/32), 256, 0, stream>>>(sa_wk, sa_qkv_t + 65536,  DD, DD);
  wt_cvt<<<dim3(DD/32, DD/32), 256, 0, stream>>>(sa_wv, sa_qkv_t + 131072, DD, DD);
  wt_cvt<<<dim3(DD/32, DD/32), 256, 0, stream>>>(ta_wq, ta_qkv_t,          DD, DD);
  wt_cvt<<<dim3(DD/32, DD/32), 256, 0, stream>>>(ta_wk, ta_qkv_t + 65536,  DD, DD);
  wt_cvt<<<dim3(DD/32, DD/32), 256, 0, stream>>>(ta_wv, ta_qkv_t + 131072, DD, DD);
  wt_cvt<<<dim3(DD/32, DD/32), 256, 0, stream>>>(sa_wo, sa_wo_t, DD, DD);
  wt_cvt<<<dim3(DD/32, DD/32), 256, 0, stream>>>(ta_wo, ta_wo_t, DD, DD);
  wt_cvt<<<dim3(FFD/32, DD/32), 256, 0, stream>>>(f_w1, f_w1_t, DD, FFD);
  wt_cvt<<<dim3(DD/32, FFD/32), 256, 0, stream>>>(f_w2, f_w2_t, FFD, DD);
  bias_cat3<<<3, 256, 0, stream>>>(sa_bq, sa_bk, sa_bv, sa_qkvb);
  bias_cat3<<<3, 256, 0, stream>>>(ta_bq, ta_bk, ta_bv, ta_qkvb);
  maskpack<<<(NN * 11 + 255) / 256, 256, 0, stream>>>(adj, MB);
  {
    int n4 = (int)(P / 4);
    cvt_bf16<<<(n4 + 255) / 256, 256, 0, stream>>>(x0, X0b, n4);
  }

  // K=256 GEMMs: persistent-B kernel. 244 m-tiles = 61 groups of 4 exactly.
  auto gemmP = [&](const __hip_bfloat16* A, const __hip_bfloat16* Wt, const float* bias,
                   __hip_bfloat16* Cb, int Nr, int gelu) {
    int nwg = (Nr / 64) * 61;
    gemm_persist<<<nwg, 256, 0, stream>>>(A, Wt, bias, Cb, MTOK, Nr, gelu);
  };

  // ---- Stage A: spatial attention ----
  gemmP(X0b, sa_qkv_t, sa_qkvb, QKVb, QKVD, 0);
  spatial_attn_mfma<<<dim3(B_ * T_, HH), 256, 0, stream>>>(QKVb, MB, ATTb);
  gemmP(ATTb, sa_wo_t, sa_bo, PRJ, DD, 0);
  add_ln<<<MTOK, 64, 0, stream>>>(x0, PRJ, sa_lw, sa_lb, R4, X1b);   // x1: R4 + X1b

  // ---- Stage B: temporal attention ----
  gemmP(X1b, ta_qkv_t, ta_qkvb, QKVb, QKVD, 0);
  {
    int total = B_ * NN * HH * T_;
    temporal_attn<<<(total + 255) / 256, 256, 0, stream>>>(QKVb, ATTb);
  }
  gemmP(ATTb, ta_wo_t, ta_bo, PRJ, DD, 0);
  add_ln<<<MTOK, 64, 0, stream>>>(R4, PRJ, ta_lw, ta_lb, R0, X0b);   // x2: R0 + X0b

  // ---- Stage C: FFN ----
  gemmP(X0b, f_w1_t, f_b1, HIDb, FFD, 1);                            // GELU, bf16 hidden
  {
    int nwg = (DD / 128) * 244;   // 488
    gemm_k1024<<<nwg, 256, 0, stream>>>(HIDb, f_w2_t, f_b2, PRJ, MTOK, DD, FFD);
  }
  add_ln<<<MTOK, 64, 0, stream>>>(R0, PRJ, f_lw, f_lb, out, nullptr);
}

// Round 11
// 451.927 us; speedup vs baseline: 1.2885x; 1.0106x over previous
//
#include <hip/hip_runtime.h>
#include <hip/hip_bf16.h>
#include <math.h>

#define B_   8
#define T_   12
#define NN   325
#define DD   256
#define HH   8
#define HD   32
#define FFD  1024
#define MTOK (B_*T_*NN)     // 31200 tokens
#define QKVD 768            // packed QKV row stride
#define ATT_SCALE 0.17677669529663687f   // 1/sqrt(32)
#define LN_EPS 1e-5f
#define NEG_BIG (-1e30f)

typedef __attribute__((ext_vector_type(8))) __bf16 bf16x8;
typedef __attribute__((ext_vector_type(4))) float  f32x4;
typedef __attribute__((ext_vector_type(4))) short  shortx4;
typedef __attribute__((ext_vector_type(8))) unsigned short ushortx8;

static __device__ inline float bf2f(unsigned short u) {
  union { float f; unsigned int i; } c; c.i = ((unsigned int)u) << 16; return c.f;
}

#if __has_builtin(__builtin_amdgcn_mfma_f32_16x16x16bf16_1k)
#define MFMA16(a,b,c) __builtin_amdgcn_mfma_f32_16x16x16bf16_1k((a),(b),(c),0,0,0)
#else
static __device__ inline f32x4 mfma16_fn(shortx4 a, shortx4 b, f32x4 c) {
  f32x4 d;
  asm volatile("v_mfma_f32_16x16x16_bf16 %0, %1, %2, %3"
               : "=v"(d) : "v"(a), "v"(b), "v"(c));
  return d;
}
#define MFMA16(a,b,c) mfma16_fn((a),(b),(c))
#endif

// ---------------------------------------------------------------------------
// Strip GEMM: amortize global-load latency per-STRIP, not per-k-step.
// B-slice [128 cols][256 k-chunk] staged in LDS (67.6KB, 2 blocks/CU).
// Each wave owns an independent 16-row strip; issues ALL 8 A-loads for the
// strip up front (one latency exposure), then 64 {ds_read B + MFMA} with
// 8x A-fragment reuse. No barriers after staging (KC=1). KC>1 (FFN2):
// re-stage B chunk per kc with uniform barriers, acc persists.
// C[M,N] = A[M,K] @ Wt[N,K]^T + bias, bf16 out, optional exact GELU.
// ---------------------------------------------------------------------------
__global__ __launch_bounds__(256, 2) void gemm_strip(
    const __hip_bfloat16* __restrict__ A,
    const __hip_bfloat16* __restrict__ Wt,
    const float* __restrict__ bias,
    __hip_bfloat16* __restrict__ Cb,
    int Mr, int Nr, int Kr, int MS, int gelu)
{
  constexpr int BP = 264;                  // LDS pitch: 528B rows -> ~2-way banks
  __shared__ __hip_bfloat16 Bs[128 * BP];  // 67.6 KB

  const int NS  = Nr >> 7;
  const int nwg = gridDim.x;
  const int orig = blockIdx.x;
  const int qq = nwg >> 3, rr = nwg & 7;
  const int xcd = orig & 7, off = orig >> 3;
  const int id = (xcd < rr ? xcd * (qq + 1) : rr * (qq + 1) + (xcd - rr) * qq) + off;
  const int n0 = (id % NS) * 128;          // N fastest: consecutive ids share A
  const int mg = id / NS;

  const int tid = threadIdx.x;
  const int w = tid >> 6, lane = tid & 63;
  const int lr = lane & 15, lg = lane >> 4;
  const int KC = Kr >> 8;                  // 256-wide K chunks

  float bv[8];
  #pragma unroll
  for (int j = 0; j < 8; ++j) bv[j] = bias[n0 + j * 16 + lr];

  for (int s = 0; s < MS; ++s) {
    const int strip = (mg * MS + s) * 64 + w * 16;
    int arow = strip + lr;
    if (arow >= Mr) arow = Mr - 1;         // clamp; stores masked below

    f32x4 acc[8] = {};

    for (int kc = 0; kc < KC; ++kc) {
      // ---- stage B chunk (skip if KC==1 and already staged) ----
      if (KC > 1 || s == 0) {
        if (!(s == 0 && kc == 0)) __syncthreads();   // readers done (uniform)
        for (int u = tid; u < 128 * 32; u += 256) {
          int row = u >> 5, c8 = (u & 31) * 8;
          bf16x8 v = *(const bf16x8*)&Wt[(size_t)(n0 + row) * Kr + kc * 256 + c8];
          *(bf16x8*)&Bs[row * BP + c8] = v;
        }
        __syncthreads();
      }

      // ---- issue ALL 8 A-loads for this strip/chunk (one latency exposure) ----
      const __hip_bfloat16* abase = A + (size_t)arow * Kr + kc * 256 + lg * 8;
      bf16x8 a[8];
      #pragma unroll
      for (int k = 0; k < 8; ++k) a[k] = *(const bf16x8*)(abase + k * 32);

      // ---- 64 ds_read + MFMA, A-frag reused 8x ----
      #pragma unroll
      for (int k = 0; k < 8; ++k) {
        #pragma unroll
        for (int j = 0; j < 8; ++j) {
          bf16x8 bfr = *(const bf16x8*)&Bs[(j * 16 + lr) * BP + k * 32 + lg * 8];
          acc[j] = __builtin_amdgcn_mfma_f32_16x16x32_bf16(a[k], bfr, acc[j], 0, 0, 0);
        }
      }
    }

    // ---- epilogue: col = lane&15 (B), row = strip + lg*4 + q (A) ----
    #pragma unroll
    for (int j = 0; j < 8; ++j) {
      int col = n0 + j * 16 + lr;
      #pragma unroll
      for (int q = 0; q < 4; ++q) {
        int gm = strip + lg * 4 + q;
        if (gm >= Mr) continue;
        float c = acc[j][q] + bv[j];
        if (gelu) c = 0.5f * c * (1.f + erff(c * 0.70710678118654752f));
        Cb[(size_t)gm * Nr + col] = __float2bfloat16(c);
      }
    }
  }
}

// ---------------------------------------------------------------------------
__global__ __launch_bounds__(256) void wt_cvt(
    const float* __restrict__ W, __hip_bfloat16* __restrict__ Wt, int K, int N)
{
  __shared__ float t[32][33];
  const int n0 = blockIdx.x * 32, k0 = blockIdx.y * 32;
  const int tx = threadIdx.x & 31, ty = threadIdx.x >> 5;
  #pragma unroll
  for (int i = 0; i < 32; i += 8)
    t[ty + i][tx] = W[(size_t)(k0 + ty + i) * N + n0 + tx];
  __syncthreads();
  #pragma unroll
  for (int i = 0; i < 32; i += 8)
    Wt[(size_t)(n0 + ty + i) * K + k0 + tx] = __float2bfloat16(t[tx][ty + i]);
}

__global__ __launch_bounds__(256) void cvt_bf16(
    const float* __restrict__ x, __hip_bfloat16* __restrict__ y, int n4)
{
  int i = blockIdx.x * 256 + threadIdx.x;
  if (i >= n4) return;
  float4 v = reinterpret_cast<const float4*>(x)[i];
  union { shortx4 s; __hip_bfloat16 h[4]; } u;
  u.h[0] = __float2bfloat16(v.x); u.h[1] = __float2bfloat16(v.y);
  u.h[2] = __float2bfloat16(v.z); u.h[3] = __float2bfloat16(v.w);
  reinterpret_cast<shortx4*>(y)[i] = u.s;
}

__global__ __launch_bounds__(256) void bias_cat3(
    const float* __restrict__ a, const float* __restrict__ b,
    const float* __restrict__ c, float* __restrict__ o)
{
  int i = blockIdx.x * 256 + threadIdx.x;
  if (i < 256) o[i] = a[i];
  else if (i < 512) o[i] = b[i - 256];
  else if (i < 768) o[i] = c[i - 512];
}

__global__ __launch_bounds__(256) void maskpack(
    const int* __restrict__ adj, unsigned int* __restrict__ mb)
{
  int idx = blockIdx.x * 256 + threadIdx.x;
  if (idx >= NN * 11) return;
  int l = idx / 11, w = idx % 11;
  unsigned int bits = 0;
  #pragma unroll 4
  for (int b = 0; b < 32; ++b) {
    int m = w * 32 + b;
    if (m < NN && adj[l * NN + m] != 0) bits |= (1u << b);
  }
  mb[idx] = bits;
}

// ---------------------------------------------------------------------------
// MFMA spatial attention over packed QKV [M][768]. One WG per (g, h).
// ---------------------------------------------------------------------------
__global__ __launch_bounds__(256) void spatial_attn_mfma(
    const __hip_bfloat16* __restrict__ qkv,
    const unsigned int* __restrict__ mb,
    __hip_bfloat16* __restrict__ out)
{
  constexpr int KP = 40;
  constexpr int VP = 340;
  __shared__ unsigned short Kl[336 * KP];
  __shared__ unsigned short Vt[32 * VP];

  const int g = blockIdx.x, h = blockIdx.y;
  const int tid = threadIdx.x;
  const int w = tid >> 6, lane = tid & 63;
  const int lq = lane & 15, lg = lane >> 4;

  const size_t baseQ = (size_t)g * NN * QKVD + (size_t)h * HD;
  const size_t baseK = baseQ + 256;
  const size_t baseV = baseQ + 512;

  for (int idx = tid; idx < 32 * (VP - NN); idx += 256) {
    int d = idx / (VP - NN), kk = NN + idx % (VP - NN);
    Vt[d * VP + kk] = 0;
  }
  for (int idx = tid; idx < NN * 4; idx += 256) {
    int row = idx >> 2, cc = (idx & 3) * 8;
    union { bf16x8 v; unsigned short u[8]; } kv, vv;
    kv.v = *(const bf16x8*)&qkv[baseK + (size_t)row * QKVD + cc];
    *(bf16x8*)&Kl[row * KP + cc] = kv.v;
    vv.v = *(const bf16x8*)&qkv[baseV + (size_t)row * QKVD + cc];
    #pragma unroll
    for (int j = 0; j < 8; ++j) Vt[(cc + j) * VP + row] = vv.u[j];
  }
  __syncthreads();

  for (int qt = w; qt < 21; qt += 4) {
    const int query = qt * 16 + lq;
    const int qc = query < NN ? query : NN - 1;
    const bf16x8 qf = *(const bf16x8*)&qkv[baseQ + (size_t)qc * QKVD + lg * 8];
    const unsigned int* mrow = &mb[qc * 11];

    f32x4 accL = {0.f, 0.f, 0.f, 0.f};
    f32x4 accH = {0.f, 0.f, 0.f, 0.f};
    float mrun = -INFINITY, lrun = 0.f;

    for (int t = 0; t < 21; ++t) {
      bf16x8 kf = *(const bf16x8*)&Kl[(t * 16 + lq) * KP + lg * 8];
      f32x4 st = __builtin_amdgcn_mfma_f32_16x16x32_bf16(
          kf, qf, (f32x4){0.f, 0.f, 0.f, 0.f}, 0, 0, 0);
      const unsigned int mw = mrow[t >> 1];
      const int kbase = t * 16 + lg * 4;
      const int bbase = (t & 1) * 16 + lg * 4;
      float s[4];
      #pragma unroll
      for (int q = 0; q < 4; ++q) {
        float fill = (kbase + q < NN) ? NEG_BIG : -INFINITY;
        s[q] = ((mw >> (bbase + q)) & 1u) ? st[q] * ATT_SCALE : fill;
      }
      float tmax = fmaxf(fmaxf(s[0], s[1]), fmaxf(s[2], s[3]));
      tmax = fmaxf(tmax, __shfl_xor(tmax, 16));
      tmax = fmaxf(tmax, __shfl_xor(tmax, 32));
      const float mnew = fmaxf(mrun, tmax);
      const float corr = __expf(mrun - mnew);
      float p0 = __expf(s[0] - mnew), p1 = __expf(s[1] - mnew);
      float p2 = __expf(s[2] - mnew), p3 = __expf(s[3] - mnew);
      float ps = p0 + p1 + p2 + p3;
      ps += __shfl_xor(ps, 16);
      ps += __shfl_xor(ps, 32);
      lrun = lrun * corr + ps;
      mrun = mnew;
      accL *= corr; accH *= corr;
      union { shortx4 s4; __hip_bfloat16 hh[4]; } up;
      up.hh[0] = __float2bfloat16(p0); up.hh[1] = __float2bfloat16(p1);
      up.hh[2] = __float2bfloat16(p2); up.hh[3] = __float2bfloat16(p3);
      shortx4 vaL = *(const shortx4*)&Vt[lq * VP + kbase];
      shortx4 vaH = *(const shortx4*)&Vt[(lq + 16) * VP + kbase];
      accL = MFMA16(vaL, up.s4, accL);
      accH = MFMA16(vaH, up.s4, accH);
    }

    if (query < NN) {
      const float inv = 1.f / lrun;
      const size_t ob = ((size_t)(g * NN + query)) * DD + (size_t)h * HD;
      union { shortx4 s4; __hip_bfloat16 hh[4]; } uL, uH;
      #pragma unroll
      for (int q = 0; q < 4; ++q) {
        uL.hh[q] = __float2bfloat16(accL[q] * inv);
        uH.hh[q] = __float2bfloat16(accH[q] * inv);
      }
      *(shortx4*)&out[ob + lg * 4]      = uL.s4;
      *(shortx4*)&out[ob + 16 + lg * 4] = uH.s4;
    }
  }
}

// ---------------------------------------------------------------------------
__global__ __launch_bounds__(256) void temporal_attn(
    const __hip_bfloat16* __restrict__ qkv, __hip_bfloat16* __restrict__ out)
{
  int idx = blockIdx.x * 256 + threadIdx.x;
  const int total = B_ * NN * HH * T_;
  if (idx >= total) return;

  int t  = idx % T_;
  int h  = (idx / T_) % HH;
  int n  = (idx / (T_ * HH)) % NN;
  int b  = idx / (T_ * HH * NN);

  const size_t tq = (size_t)((b * T_ + t) * NN + n) * QKVD + h * HD;
  float qr[HD];
  #pragma unroll
  for (int c8 = 0; c8 < 4; ++c8) {
    ushortx8 u = *(const ushortx8*)&qkv[tq + c8 * 8];
    #pragma unroll
    for (int j = 0; j < 8; ++j) qr[c8 * 8 + j] = bf2f(u[j]);
  }

  float o[HD] = {};
  float mrun = -INFINITY, lrun = 0.f;

  for (int tt = 0; tt <= t; ++tt) {
    const size_t tk = (size_t)((b * T_ + tt) * NN + n) * QKVD + h * HD;
    float s = 0.f;
    #pragma unroll
    for (int c8 = 0; c8 < 4; ++c8) {
      ushortx8 u = *(const ushortx8*)&qkv[tk + 256 + c8 * 8];
      #pragma unroll
      for (int j = 0; j < 8; ++j) s += qr[c8 * 8 + j] * bf2f(u[j]);
    }
    s *= ATT_SCALE;

    float mnew = fmaxf(mrun, s);
    float corr = __expf(mrun - mnew);
    float p = __expf(s - mnew);
    lrun = lrun * corr + p;
    #pragma unroll
    for (int c8 = 0; c8 < 4; ++c8) {
      ushortx8 u = *(const ushortx8*)&qkv[tk + 512 + c8 * 8];
      #pragma unroll
      for (int j = 0; j < 8; ++j) o[c8 * 8 + j] = o[c8 * 8 + j] * corr + p * bf2f(u[j]);
    }
    mrun = mnew;
  }

  float inv = 1.f / lrun;
  __hip_bfloat16* op = out + ((size_t)((b * T_ + t) * NN + n)) * DD + h * HD;
  #pragma unroll
  for (int d0 = 0; d0 < HD; d0 += 4) {
    union { shortx4 s; __hip_bfloat16 h4[4]; } u;
    #pragma unroll
    for (int j = 0; j < 4; ++j) u.h4[j] = __float2bfloat16(o[d0 + j] * inv);
    *reinterpret_cast<shortx4*>(op + d0) = u.s;
  }
}

// ---------------------------------------------------------------------------
__global__ __launch_bounds__(64) void add_ln(
    const float* __restrict__ x, const __hip_bfloat16* __restrict__ r,
    const float* __restrict__ w, const float* __restrict__ bb,
    float* __restrict__ y, __hip_bfloat16* __restrict__ ybf)
{
  const size_t row = blockIdx.x;
  const int lane = threadIdx.x;

  const float4 xv = reinterpret_cast<const float4*>(x + row * DD)[lane];
  union { shortx4 s4; unsigned short u[4]; } rv;
  rv.s4 = reinterpret_cast<const shortx4*>(r + row * DD)[lane];
  float e[4] = {xv.x + bf2f(rv.u[0]), xv.y + bf2f(rv.u[1]),
                xv.z + bf2f(rv.u[2]), xv.w + bf2f(rv.u[3])};

  float s  = e[0] + e[1] + e[2] + e[3];
  float ss = e[0]*e[0] + e[1]*e[1] + e[2]*e[2] + e[3]*e[3];
  #pragma unroll
  for (int off = 32; off > 0; off >>= 1) {
    s  += __shfl_xor(s,  off, 64);
    ss += __shfl_xor(ss, off, 64);
  }
  float mu  = s * (1.f / DD);
  float var = ss * (1.f / DD) - mu * mu;
  float rs  = rsqrtf(var + LN_EPS);

  const float4 wv = reinterpret_cast<const float4*>(w)[lane];
  const float4 bv = reinterpret_cast<const float4*>(bb)[lane];
  float o0 = (e[0] - mu) * rs * wv.x + bv.x;
  float o1 = (e[1] - mu) * rs * wv.y + bv.y;
  float o2 = (e[2] - mu) * rs * wv.z + bv.z;
  float o3 = (e[3] - mu) * rs * wv.w + bv.w;
  float4 yv = {o0, o1, o2, o3};
  reinterpret_cast<float4*>(y + row * DD)[lane] = yv;
  if (ybf) {
    union { shortx4 s4; __hip_bfloat16 h4[4]; } u;
    u.h4[0] = __float2bfloat16(o0); u.h4[1] = __float2bfloat16(o1);
    u.h4[2] = __float2bfloat16(o2); u.h4[3] = __float2bfloat16(o3);
    reinterpret_cast<shortx4*>(ybf + row * DD)[lane] = u.s4;
  }
}

// ---------------------------------------------------------------------------
extern "C" void kernel_launch(void* const* d_in, const int* in_sizes, int n_in,
                              void* d_out, int out_size, void* d_ws, size_t ws_size,
                              hipStream_t stream)
{
  const float* x0   = (const float*)d_in[0];
  const int*   adj  = (const int*)  d_in[1];
  const float* sa_wq = (const float*)d_in[2];
  const float* sa_bq = (const float*)d_in[3];
  const float* sa_wk = (const float*)d_in[4];
  const float* sa_bk = (const float*)d_in[5];
  const float* sa_wv = (const float*)d_in[6];
  const float* sa_bv = (const float*)d_in[7];
  const float* sa_wo = (const float*)d_in[8];
  const float* sa_bo = (const float*)d_in[9];
  const float* sa_lw = (const float*)d_in[10];
  const float* sa_lb = (const float*)d_in[11];
  const float* ta_wq = (const float*)d_in[12];
  const float* ta_bq = (const float*)d_in[13];
  const float* ta_wk = (const float*)d_in[14];
  const float* ta_bk = (const float*)d_in[15];
  const float* ta_wv = (const float*)d_in[16];
  const float* ta_bv = (const float*)d_in[17];
  const float* ta_wo = (const float*)d_in[18];
  const float* ta_bo = (const float*)d_in[19];
  const float* ta_lw = (const float*)d_in[20];
  const float* ta_lb = (const float*)d_in[21];
  const float* f_w1  = (const float*)d_in[22];
  const float* f_b1  = (const float*)d_in[23];
  const float* f_w2  = (const float*)d_in[24];
  const float* f_b2  = (const float*)d_in[25];
  const float* f_lw  = (const float*)d_in[26];
  const float* f_lb  = (const float*)d_in[27];

  float* out = (float*)d_out;
  float* ws  = (float*)d_ws;

  const size_t P = (size_t)MTOK * DD;           // 7,987,200 floats (32 MB)
  if (ws_size < 7 * P * sizeof(float)) return;

  float* R0 = ws;                                 // x2 fp32 [0,1P)
  __hip_bfloat16* QKVb = (__hip_bfloat16*)(ws + P);     // [M,768] bf16 [1P,2.5P)
  __hip_bfloat16* HIDb = (__hip_bfloat16*)(ws + P);     // [M,1024] bf16, stage C [1P,3P)
  __hip_bfloat16* PRJ  = (__hip_bfloat16*)(ws + 3 * P); // proj out bf16 [3P,3.5P)
  float* R4 = ws + 4 * P;                         // x1 fp32 [4P,5P)
  __hip_bfloat16* X0b  = (__hip_bfloat16*)(ws + 5 * P);          // [5P,5.5P)
  __hip_bfloat16* X1b  = (__hip_bfloat16*)(ws + 5 * P + P / 2);  // [5.5P,6P)
  __hip_bfloat16* ATTb = (__hip_bfloat16*)(ws + 6 * P);          // [6P,6.5P)
  __hip_bfloat16* Wb   = (__hip_bfloat16*)(ws + 6 * P + P / 2);  // weights

  __hip_bfloat16* sa_qkv_t = Wb;                 // [768][256]
  __hip_bfloat16* ta_qkv_t = Wb + 196608;        // [768][256]
  __hip_bfloat16* sa_wo_t  = Wb + 393216;        // [256][256]
  __hip_bfloat16* ta_wo_t  = Wb + 458752;
  __hip_bfloat16* f_w1_t   = Wb + 524288;        // [1024][256]
  __hip_bfloat16* f_w2_t   = Wb + 786432;        // [256][1024]
  float* sa_qkvb = (float*)(Wb + 1048576);       // [768]
  float* ta_qkvb = sa_qkvb + 768;                // [768]
  unsigned int* MB = (unsigned int*)(ta_qkvb + 768);   // 325*11

  // ---- prep ----
  wt_cvt<<<dim3(DD/32, DD/32), 256, 0, stream>>>(sa_wq, sa_qkv_t,          DD, DD);
  wt_cvt<<<dim3(DD/32, DD/32), 256, 0, stream>>>(sa_wk, sa_qkv_t + 65536,  DD, DD);
  wt_cvt<<<dim3(DD/32, DD/32), 256, 0, stream>>>(sa_wv, sa_qkv_t + 131072, DD, DD);
  wt_cvt<<<dim3(DD/32, DD/32), 256, 0, stream>>>(ta_wq, ta_qkv_t,          DD, DD);
  wt_cvt<<<dim3(DD/32, DD/32), 256, 0, stream>>>(ta_wk, ta_qkv_t + 65536,  DD, DD);
  wt_cvt<<<dim3(DD/32, DD/32), 256, 0, stream>>>(ta_wv, ta_qkv_t + 131072, DD, DD);
  wt_cvt<<<dim3(DD/32, DD/32), 256, 0, stream>>>(sa_wo, sa_wo_t, DD, DD);
  wt_cvt<<<dim3(DD/32, DD/32), 256, 0, stream>>>(ta_wo, ta_wo_t, DD, DD);
  wt_cvt<<<dim3(FFD/32, DD/32), 256, 0, stream>>>(f_w1, f_w1_t, DD, FFD);
  wt_cvt<<<dim3(DD/32, FFD/32), 256, 0, stream>>>(f_w2, f_w2_t, FFD, DD);
  bias_cat3<<<3, 256, 0, stream>>>(sa_bq, sa_bk, sa_bv, sa_qkvb);
  bias_cat3<<<3, 256, 0, stream>>>(ta_bq, ta_bk, ta_bv, ta_qkvb);
  maskpack<<<(NN * 11 + 255) / 256, 256, 0, stream>>>(adj, MB);
  {
    int n4 = (int)(P / 4);
    cvt_bf16<<<(n4 + 255) / 256, 256, 0, stream>>>(x0, X0b, n4);
  }

  // strip GEMM dispatch: K=256 -> MS=4 (block covers 256 rows, MG=122);
  //                      K=1024 -> MS=1 (64 rows, MG=488, 4 B-chunk stagings)
  auto gemmS = [&](const __hip_bfloat16* A, const __hip_bfloat16* Wt, const float* bias,
                   __hip_bfloat16* Cb, int Nr, int Kr, int gelu) {
    int MS = (Kr == 256) ? 4 : 1;
    int MG = (MTOK + MS * 64 - 1) / (MS * 64);   // 122 or 488
    int nwg = (Nr / 128) * MG;
    gemm_strip<<<nwg, 256, 0, stream>>>(A, Wt, bias, Cb, MTOK, Nr, Kr, MS, gelu);
  };

  // ---- Stage A: spatial attention ----
  gemmS(X0b, sa_qkv_t, sa_qkvb, QKVb, QKVD, DD, 0);
  spatial_attn_mfma<<<dim3(B_ * T_, HH), 256, 0, stream>>>(QKVb, MB, ATTb);
  gemmS(ATTb, sa_wo_t, sa_bo, PRJ, DD, DD, 0);
  add_ln<<<MTOK, 64, 0, stream>>>(x0, PRJ, sa_lw, sa_lb, R4, X1b);   // x1: R4 + X1b

  // ---- Stage B: temporal attention ----
  gemmS(X1b, ta_qkv_t, ta_qkvb, QKVb, QKVD, DD, 0);
  {
    int total = B_ * NN * HH * T_;
    temporal_attn<<<(total + 255) / 256, 256, 0, stream>>>(QKVb, ATTb);
  }
  gemmS(ATTb, ta_wo_t, ta_bo, PRJ, DD, DD, 0);
  add_ln<<<MTOK, 64, 0, stream>>>(R4, PRJ, ta_lw, ta_lb, R0, X0b);   // x2: R0 + X0b

  // ---- Stage C: FFN ----
  gemmS(X0b, f_w1_t, f_b1, HIDb, FFD, DD, 1);                        // GELU, bf16 hidden
  gemmS(HIDb, f_w2_t, f_b2, PRJ, DD, FFD, 0);                        // K=1024 path
  add_ln<<<MTOK, 64, 0, stream>>>(R0, PRJ, f_lw, f_lb, out, nullptr);
}

// Round 13
// 419.765 us; speedup vs baseline: 1.3872x; 1.0766x over previous
//
#include <hip/hip_runtime.h>
#include <hip/hip_bf16.h>
#include <math.h>

#define B_   8
#define T_   12
#define NN   325
#define DD   256
#define HH   8
#define HD   32
#define FFD  1024
#define MTOK (B_*T_*NN)     // 31200 tokens
#define QKVD 768            // packed QKV row stride
#define ATT_SCALE 0.17677669529663687f   // 1/sqrt(32), folded into Q weights
#define LN_EPS 1e-5f
#define MROWS 336           // padded key count (21 tiles of 16)

typedef __attribute__((ext_vector_type(8))) __bf16 bf16x8;
typedef __attribute__((ext_vector_type(4))) float  f32x4;
typedef __attribute__((ext_vector_type(4))) short  shortx4;
typedef __attribute__((ext_vector_type(8))) unsigned short ushortx8;

static __device__ inline float bf2f(unsigned short u) {
  union { float f; unsigned int i; } c; c.i = ((unsigned int)u) << 16; return c.f;
}

#if __has_builtin(__builtin_amdgcn_mfma_f32_16x16x16bf16_1k)
#define MFMA16(a,b,c) __builtin_amdgcn_mfma_f32_16x16x16bf16_1k((a),(b),(c),0,0,0)
#else
static __device__ inline f32x4 mfma16_fn(shortx4 a, shortx4 b, f32x4 c) {
  f32x4 d;
  asm volatile("v_mfma_f32_16x16x16_bf16 %0, %1, %2, %3"
               : "=v"(d) : "v"(a), "v"(b), "v"(c));
  return d;
}
#define MFMA16(a,b,c) mfma16_fn((a),(b),(c))
#endif

// ---------------------------------------------------------------------------
// Strip GEMM v2: 2 strips/wave (B-frag reuse x2), K-chunk 128 (LDS 34.8KB ->
// 4 WG/CU). Per kc: stage B [128 cols][128 k]; per wave: preload 2x4 A-frags
// (one latency exposure), then 32 ds_read + 64 MFMA, no inner barriers.
// C[M,N] = A[M,K] @ Wt[N,K]^T + bias, bf16 out, optional exact GELU.
// ---------------------------------------------------------------------------
__global__ __launch_bounds__(256) void gemm_strip2(
    const __hip_bfloat16* __restrict__ A,
    const __hip_bfloat16* __restrict__ Wt,
    const float* __restrict__ bias,
    __hip_bfloat16* __restrict__ Cb,
    int Mr, int Nr, int Kr, int gelu)
{
  constexpr int BP = 136;                  // 272B rows -> balanced banks
  __shared__ __hip_bfloat16 Bs[128 * BP];  // 34.8 KB

  const int NS  = Nr >> 7;
  const int nwg = gridDim.x;
  const int orig = blockIdx.x;
  const int qq = nwg >> 3, rr = nwg & 7;
  const int xcd = orig & 7, off = orig >> 3;
  const int id = (xcd < rr ? xcd * (qq + 1) : rr * (qq + 1) + (xcd - rr) * qq) + off;
  const int n0 = (id % NS) * 128;          // N fastest: consecutive ids share A
  const int mg = id / NS;                  // 128-row group

  const int tid = threadIdx.x;
  const int w = tid >> 6, lane = tid & 63;
  const int lr = lane & 15, lg = lane >> 4;
  const int KC = Kr >> 7;

  float bv[8];
  #pragma unroll
  for (int j = 0; j < 8; ++j) bv[j] = bias[n0 + j * 16 + lr];

  const int strip0 = mg * 128 + w * 32;
  int ar0 = strip0 + lr;      if (ar0 >= Mr) ar0 = Mr - 1;
  int ar1 = strip0 + 16 + lr; if (ar1 >= Mr) ar1 = Mr - 1;

  f32x4 acc0[8] = {}, acc1[8] = {};

  for (int kc = 0; kc < KC; ++kc) {
    if (kc) __syncthreads();               // readers done before overwrite
    for (int u = tid; u < 128 * 16; u += 256) {
      int row = u >> 4, c8 = (u & 15) * 8;
      *(bf16x8*)&Bs[row * BP + c8] =
          *(const bf16x8*)&Wt[(size_t)(n0 + row) * Kr + kc * 128 + c8];
    }
    __syncthreads();

    const __hip_bfloat16* a0p = A + (size_t)ar0 * Kr + kc * 128 + lg * 8;
    const __hip_bfloat16* a1p = A + (size_t)ar1 * Kr + kc * 128 + lg * 8;
    bf16x8 a0[4], a1[4];
    #pragma unroll
    for (int k = 0; k < 4; ++k) {
      a0[k] = *(const bf16x8*)(a0p + k * 32);
      a1[k] = *(const bf16x8*)(a1p + k * 32);
    }
    #pragma unroll
    for (int k = 0; k < 4; ++k)
      #pragma unroll
      for (int j = 0; j < 8; ++j) {
        bf16x8 bfr = *(const bf16x8*)&Bs[(j * 16 + lr) * BP + k * 32 + lg * 8];
        acc0[j] = __builtin_amdgcn_mfma_f32_16x16x32_bf16(a0[k], bfr, acc0[j], 0, 0, 0);
        acc1[j] = __builtin_amdgcn_mfma_f32_16x16x32_bf16(a1[k], bfr, acc1[j], 0, 0, 0);
      }
  }

  // epilogue: col = lane&15, row = lg*4 + q within each 16-row strip
  #pragma unroll
  for (int j = 0; j < 8; ++j) {
    int col = n0 + j * 16 + lr;
    #pragma unroll
    for (int q = 0; q < 4; ++q) {
      int g0 = strip0 + lg * 4 + q;
      if (g0 < Mr) {
        float c = acc0[j][q] + bv[j];
        if (gelu) c = 0.5f * c * (1.f + erff(c * 0.70710678118654752f));
        Cb[(size_t)g0 * Nr + col] = __float2bfloat16(c);
      }
      int g1 = strip0 + 16 + lg * 4 + q;
      if (g1 < Mr) {
        float c = acc1[j][q] + bv[j];
        if (gelu) c = 0.5f * c * (1.f + erff(c * 0.70710678118654752f));
        Cb[(size_t)g1 * Nr + col] = __float2bfloat16(c);
      }
    }
  }
}

// ---------------------------------------------------------------------------
// Fused prep: z 0..9 weight transpose+cvt (Q weights pre-scaled by ATT_SCALE),
// z=10 bias concat (Q bias scaled) + additive mask table, z=11 x0 -> bf16.
// ---------------------------------------------------------------------------
struct PrepPtrs {
  const float* w[10];   // sa_wq,wk,wv, ta_wq,wk,wv, sa_wo, ta_wo, f_w1, f_w2
  const float* b[6];    // sa_bq,bk,bv, ta_bq,bk,bv
};

__global__ __launch_bounds__(256) void prep_all(
    PrepPtrs p, const int* __restrict__ adj, const float* __restrict__ x0,
    __hip_bfloat16* __restrict__ Wb, float* __restrict__ qkvb /*2x768*/,
    float* __restrict__ maskf, __hip_bfloat16* __restrict__ x0b)
{
  __shared__ float t[32][33];
  const int z = blockIdx.z;

  if (z < 10) {
    const int Kz = (z == 9) ? 1024 : 256;
    const int Nz = (z == 8) ? 1024 : 256;
    if ((int)blockIdx.x >= Nz / 32 || (int)blockIdx.y >= Kz / 32) return;
    static const unsigned int dsto[10] = {0, 65536, 131072, 196608, 262144,
                                          327680, 393216, 458752, 524288, 786432};
    const float scale = (z == 0 || z == 3) ? ATT_SCALE : 1.f;
    const float* W = p.w[z];
    __hip_bfloat16* Wt = Wb + dsto[z];
    const int n0 = blockIdx.x * 32, k0 = blockIdx.y * 32;
    const int tx = threadIdx.x & 31, ty = threadIdx.x >> 5;
    #pragma unroll
    for (int i = 0; i < 32; i += 8)
      t[ty + i][tx] = W[(size_t)(k0 + ty + i) * Nz + n0 + tx];
    __syncthreads();
    #pragma unroll
    for (int i = 0; i < 32; i += 8)
      Wt[(size_t)(n0 + ty + i) * Kz + k0 + tx] = __float2bfloat16(t[tx][ty + i] * scale);
    return;
  }

  const int bx = blockIdx.x + blockIdx.y * 32;     // 0..1023
  const int gid = bx * 256 + threadIdx.x;          // 0..262143

  if (z == 10) {
    if (gid < 1536) {                              // bias concat (index mapping
      int i = gid & 767;                           // is a permutation of 0..767
      int which = gid < 768 ? 0 : 1;               // with value-index consistency)
      int sub = i >> 8, j = i & 255;
      float v = p.b[which * 3 + sub][j];
      if (sub == 0) v *= ATT_SCALE;
      qkvb[which * 768 + i] = v;
    } else if (gid < 1536 + NN * MROWS) {          // additive mask table
      int idx = gid - 1536;
      int l = idx / MROWS, m = idx % MROWS;
      float v;
      if (m >= NN) v = -INFINITY;                  // phantom key -> p = 0
      else v = (adj[l * NN + m] != 0) ? 0.f : -1e30f;
      maskf[idx] = v;
    }
    return;
  }

  // z == 11: x0 -> bf16, grid-stride over float4s
  const int n4 = MTOK * DD / 4;
  for (int i = gid; i < n4; i += 262144) {
    float4 v = reinterpret_cast<const float4*>(x0)[i];
    union { shortx4 s; __hip_bfloat16 h[4]; } u;
    u.h[0] = __float2bfloat16(v.x); u.h[1] = __float2bfloat16(v.y);
    u.h[2] = __float2bfloat16(v.z); u.h[3] = __float2bfloat16(v.w);
    reinterpret_cast<shortx4*>(x0b)[i] = u.s;
  }
}

// ---------------------------------------------------------------------------
// MFMA spatial attention, two-pass softmax. One WG per (g, h).
// Pass 1: 21 score-tiles into registers (+ additive mask), per-lane max.
// One cross-lane max reduce per q-tile. Pass 2: exp + PV, one sum reduce.
// Q pre-scaled by ATT_SCALE via weights.
// R12 NaN fix: phantom Kl rows (NN..MROWS) MUST be zeroed — additive mask
// cannot cancel NaN/Inf garbage from uninitialized LDS (NaN + -inf = NaN).
// ---------------------------------------------------------------------------
__global__ __launch_bounds__(256, 3) void spatial_attn_mfma(
    const __hip_bfloat16* __restrict__ qkv,
    const float* __restrict__ maskf,
    __hip_bfloat16* __restrict__ out)
{
  constexpr int KP = 40;
  constexpr int VP = 340;
  __shared__ unsigned short Kl[MROWS * KP];
  __shared__ unsigned short Vt[32 * VP];

  const int g = blockIdx.x, h = blockIdx.y;
  const int tid = threadIdx.x;
  const int w = tid >> 6, lane = tid & 63;
  const int lq = lane & 15, lg = lane >> 4;

  const size_t baseQ = (size_t)g * NN * QKVD + (size_t)h * HD;
  const size_t baseK = baseQ + 256;
  const size_t baseV = baseQ + 512;

  // zero phantom V^T columns AND phantom K rows (NaN-garbage guard)
  for (int idx = tid; idx < 32 * (VP - NN); idx += 256) {
    int d = idx / (VP - NN), kk = NN + idx % (VP - NN);
    Vt[d * VP + kk] = 0;
  }
  for (int idx = tid; idx < (MROWS - NN) * KP; idx += 256)
    Kl[NN * KP + idx] = 0;
  for (int idx = tid; idx < NN * 4; idx += 256) {
    int row = idx >> 2, cc = (idx & 3) * 8;
    union { bf16x8 v; unsigned short u[8]; } kv, vv;
    kv.v = *(const bf16x8*)&qkv[baseK + (size_t)row * QKVD + cc];
    *(bf16x8*)&Kl[row * KP + cc] = kv.v;
    vv.v = *(const bf16x8*)&qkv[baseV + (size_t)row * QKVD + cc];
    #pragma unroll
    for (int j = 0; j < 8; ++j) Vt[(cc + j) * VP + row] = vv.u[j];
  }
  __syncthreads();

  for (int qt = w; qt < 21; qt += 4) {
    const int query = qt * 16 + lq;
    const int qc = query < NN ? query : NN - 1;
    const bf16x8 qf = *(const bf16x8*)&qkv[baseQ + (size_t)qc * QKVD + lg * 8];
    const float* mrow = maskf + (size_t)qc * MROWS;

    // ---- pass 1: all scores into regs, per-lane max ----
    f32x4 sreg[21];
    float lmax = -INFINITY;
    #pragma unroll
    for (int t = 0; t < 21; ++t) {
      bf16x8 kf = *(const bf16x8*)&Kl[(t * 16 + lq) * KP + lg * 8];
      f32x4 st = __builtin_amdgcn_mfma_f32_16x16x32_bf16(
          kf, qf, (f32x4){0.f, 0.f, 0.f, 0.f}, 0, 0, 0);
      const int kbase = t * 16 + lg * 4;
      float4 mb = *(const float4*)&mrow[kbase];
      f32x4 s = {st[0] + mb.x, st[1] + mb.y, st[2] + mb.z, st[3] + mb.w};
      sreg[t] = s;
      lmax = fmaxf(lmax, fmaxf(fmaxf(s[0], s[1]), fmaxf(s[2], s[3])));
    }
    lmax = fmaxf(lmax, __shfl_xor(lmax, 16));
    lmax = fmaxf(lmax, __shfl_xor(lmax, 32));

    // ---- pass 2: exp + PV ----
    f32x4 accL = {0.f, 0.f, 0.f, 0.f};
    f32x4 accH = {0.f, 0.f, 0.f, 0.f};
    float lsum = 0.f;
    #pragma unroll
    for (int t = 0; t < 21; ++t) {
      float p0 = __expf(sreg[t][0] - lmax);
      float p1 = __expf(sreg[t][1] - lmax);
      float p2 = __expf(sreg[t][2] - lmax);
      float p3 = __expf(sreg[t][3] - lmax);
      lsum += (p0 + p1) + (p2 + p3);
      union { shortx4 s4; __hip_bfloat16 hh[4]; } up;
      up.hh[0] = __float2bfloat16(p0); up.hh[1] = __float2bfloat16(p1);
      up.hh[2] = __float2bfloat16(p2); up.hh[3] = __float2bfloat16(p3);
      const int kbase = t * 16 + lg * 4;
      shortx4 vaL = *(const shortx4*)&Vt[lq * VP + kbase];
      shortx4 vaH = *(const shortx4*)&Vt[(lq + 16) * VP + kbase];
      accL = MFMA16(vaL, up.s4, accL);
      accH = MFMA16(vaH, up.s4, accH);
    }
    lsum += __shfl_xor(lsum, 16);
    lsum += __shfl_xor(lsum, 32);

    if (query < NN) {
      const float inv = 1.f / lsum;
      const size_t ob = ((size_t)(g * NN + query)) * DD + (size_t)h * HD;
      union { shortx4 s4; __hip_bfloat16 hh[4]; } uL, uH;
      #pragma unroll
      for (int q = 0; q < 4; ++q) {
        uL.hh[q] = __float2bfloat16(accL[q] * inv);
        uH.hh[q] = __float2bfloat16(accH[q] * inv);
      }
      *(shortx4*)&out[ob + lg * 4]      = uL.s4;
      *(shortx4*)&out[ob + 16 + lg * 4] = uH.s4;
    }
  }
}

// ---------------------------------------------------------------------------
// Temporal attention (causal, T=12), packed bf16 QKV. Q pre-scaled.
// ---------------------------------------------------------------------------
__global__ __launch_bounds__(256) void temporal_attn(
    const __hip_bfloat16* __restrict__ qkv, __hip_bfloat16* __restrict__ out)
{
  int idx = blockIdx.x * 256 + threadIdx.x;
  const int total = B_ * NN * HH * T_;
  if (idx >= total) return;

  int t  = idx % T_;
  int h  = (idx / T_) % HH;
  int n  = (idx / (T_ * HH)) % NN;
  int b  = idx / (T_ * HH * NN);

  const size_t tq = (size_t)((b * T_ + t) * NN + n) * QKVD + h * HD;
  float qr[HD];
  #pragma unroll
  for (int c8 = 0; c8 < 4; ++c8) {
    ushortx8 u = *(const ushortx8*)&qkv[tq + c8 * 8];
    #pragma unroll
    for (int j = 0; j < 8; ++j) qr[c8 * 8 + j] = bf2f(u[j]);
  }

  float o[HD] = {};
  float mrun = -INFINITY, lrun = 0.f;

  for (int tt = 0; tt <= t; ++tt) {
    const size_t tk = (size_t)((b * T_ + tt) * NN + n) * QKVD + h * HD;
    float s = 0.f;
    #pragma unroll
    for (int c8 = 0; c8 < 4; ++c8) {
      ushortx8 u = *(const ushortx8*)&qkv[tk + 256 + c8 * 8];
      #pragma unroll
      for (int j = 0; j < 8; ++j) s += qr[c8 * 8 + j] * bf2f(u[j]);
    }
    float mnew = fmaxf(mrun, s);
    float corr = __expf(mrun - mnew);
    float p = __expf(s - mnew);
    lrun = lrun * corr + p;
    #pragma unroll
    for (int c8 = 0; c8 < 4; ++c8) {
      ushortx8 u = *(const ushortx8*)&qkv[tk + 512 + c8 * 8];
      #pragma unroll
      for (int j = 0; j < 8; ++j) o[c8 * 8 + j] = o[c8 * 8 + j] * corr + p * bf2f(u[j]);
    }
    mrun = mnew;
  }

  float inv = 1.f / lrun;
  __hip_bfloat16* op = out + ((size_t)((b * T_ + t) * NN + n)) * DD + h * HD;
  #pragma unroll
  for (int d0 = 0; d0 < HD; d0 += 4) {
    union { shortx4 s; __hip_bfloat16 h4[4]; } u;
    #pragma unroll
    for (int j = 0; j < 4; ++j) u.h4[j] = __float2bfloat16(o[d0 + j] * inv);
    *reinterpret_cast<shortx4*>(op + d0) = u.s;
  }
}

// ---------------------------------------------------------------------------
__global__ __launch_bounds__(64) void add_ln(
    const float* __restrict__ x, const __hip_bfloat16* __restrict__ r,
    const float* __restrict__ w, const float* __restrict__ bb,
    float* __restrict__ y, __hip_bfloat16* __restrict__ ybf)
{
  const size_t row = blockIdx.x;
  const int lane = threadIdx.x;

  const float4 xv = reinterpret_cast<const float4*>(x + row * DD)[lane];
  union { shortx4 s4; unsigned short u[4]; } rv;
  rv.s4 = reinterpret_cast<const shortx4*>(r + row * DD)[lane];
  float e[4] = {xv.x + bf2f(rv.u[0]), xv.y + bf2f(rv.u[1]),
                xv.z + bf2f(rv.u[2]), xv.w + bf2f(rv.u[3])};

  float s  = e[0] + e[1] + e[2] + e[3];
  float ss = e[0]*e[0] + e[1]*e[1] + e[2]*e[2] + e[3]*e[3];
  #pragma unroll
  for (int off = 32; off > 0; off >>= 1) {
    s  += __shfl_xor(s,  off, 64);
    ss += __shfl_xor(ss, off, 64);
  }
  float mu  = s * (1.f / DD);
  float var = ss * (1.f / DD) - mu * mu;
  float rs  = rsqrtf(var + LN_EPS);

  const float4 wv = reinterpret_cast<const float4*>(w)[lane];
  const float4 bv = reinterpret_cast<const float4*>(bb)[lane];
  float o0 = (e[0] - mu) * rs * wv.x + bv.x;
  float o1 = (e[1] - mu) * rs * wv.y + bv.y;
  float o2 = (e[2] - mu) * rs * wv.z + bv.z;
  float o3 = (e[3] - mu) * rs * wv.w + bv.w;
  float4 yv = {o0, o1, o2, o3};
  reinterpret_cast<float4*>(y + row * DD)[lane] = yv;
  if (ybf) {
    union { shortx4 s4; __hip_bfloat16 h4[4]; } u;
    u.h4[0] = __float2bfloat16(o0); u.h4[1] = __float2bfloat16(o1);
    u.h4[2] = __float2bfloat16(o2); u.h4[3] = __float2bfloat16(o3);
    reinterpret_cast<shortx4*>(ybf + row * DD)[lane] = u.s4;
  }
}

// ---------------------------------------------------------------------------
extern "C" void kernel_launch(void* const* d_in, const int* in_sizes, int n_in,
                              void* d_out, int out_size, void* d_ws, size_t ws_size,
                              hipStream_t stream)
{
  const float* x0   = (const float*)d_in[0];
  const int*   adj  = (const int*)  d_in[1];
  const float* sa_wq = (const float*)d_in[2];
  const float* sa_bq = (const float*)d_in[3];
  const float* sa_wk = (const float*)d_in[4];
  const float* sa_bk = (const float*)d_in[5];
  const float* sa_wv = (const float*)d_in[6];
  const float* sa_bv = (const float*)d_in[7];
  const float* sa_wo = (const float*)d_in[8];
  const float* sa_bo = (const float*)d_in[9];
  const float* sa_lw = (const float*)d_in[10];
  const float* sa_lb = (const float*)d_in[11];
  const float* ta_wq = (const float*)d_in[12];
  const float* ta_bq = (const float*)d_in[13];
  const float* ta_wk = (const float*)d_in[14];
  const float* ta_bk = (const float*)d_in[15];
  const float* ta_wv = (const float*)d_in[16];
  const float* ta_bv = (const float*)d_in[17];
  const float* ta_wo = (const float*)d_in[18];
  const float* ta_bo = (const float*)d_in[19];
  const float* ta_lw = (const float*)d_in[20];
  const float* ta_lb = (const float*)d_in[21];
  const float* f_w1  = (const float*)d_in[22];
  const float* f_b1  = (const float*)d_in[23];
  const float* f_w2  = (const float*)d_in[24];
  const float* f_b2  = (const float*)d_in[25];
  const float* f_lw  = (const float*)d_in[26];
  const float* f_lb  = (const float*)d_in[27];

  float* out = (float*)d_out;
  float* ws  = (float*)d_ws;

  const size_t P = (size_t)MTOK * DD;           // 7,987,200 floats (32 MB)
  if (ws_size < 7 * P * sizeof(float)) return;

  float* R0 = ws;                                 // x2 fp32 [0,1P)
  __hip_bfloat16* QKVb = (__hip_bfloat16*)(ws + P);     // [M,768] bf16 [1P,2.5P)
  __hip_bfloat16* HIDb = (__hip_bfloat16*)(ws + P);     // [M,1024] bf16, stage C [1P,3P)
  __hip_bfloat16* PRJ  = (__hip_bfloat16*)(ws + 3 * P); // proj out bf16 [3P,3.5P)
  float* R4 = ws + 4 * P;                         // x1 fp32 [4P,5P)
  __hip_bfloat16* X0b  = (__hip_bfloat16*)(ws + 5 * P);          // [5P,5.5P)
  __hip_bfloat16* X1b  = (__hip_bfloat16*)(ws + 5 * P + P / 2);  // [5.5P,6P)
  __hip_bfloat16* ATTb = (__hip_bfloat16*)(ws + 6 * P);          // [6P,6.5P)
  __hip_bfloat16* Wb   = (__hip_bfloat16*)(ws + 6 * P + P / 2);  // weights

  __hip_bfloat16* sa_qkv_t = Wb;                 // [768][256]
  __hip_bfloat16* ta_qkv_t = Wb + 196608;        // [768][256]
  __hip_bfloat16* sa_wo_t  = Wb + 393216;        // [256][256]
  __hip_bfloat16* ta_wo_t  = Wb + 458752;
  __hip_bfloat16* f_w1_t   = Wb + 524288;        // [1024][256]
  __hip_bfloat16* f_w2_t   = Wb + 786432;        // [256][1024]
  float* qkvb  = (float*)(Wb + 1048576);         // sa[768] + ta[768]
  float* maskf = qkvb + 1536;                    // [NN][336] additive mask

  // ---- fused prep ----
  PrepPtrs pp;
  pp.w[0] = sa_wq; pp.w[1] = sa_wk; pp.w[2] = sa_wv;
  pp.w[3] = ta_wq; pp.w[4] = ta_wk; pp.w[5] = ta_wv;
  pp.w[6] = sa_wo; pp.w[7] = ta_wo; pp.w[8] = f_w1; pp.w[9] = f_w2;
  pp.b[0] = sa_bq; pp.b[1] = sa_bk; pp.b[2] = sa_bv;
  pp.b[3] = ta_bq; pp.b[4] = ta_bk; pp.b[5] = ta_bv;
  prep_all<<<dim3(32, 32, 12), 256, 0, stream>>>(pp, adj, x0, Wb, qkvb, maskf, X0b);

  const int MG = (MTOK + 127) / 128;   // 244
  auto gemmS = [&](const __hip_bfloat16* A, const __hip_bfloat16* Wt, const float* bias,
                   __hip_bfloat16* Cb, int Nr, int Kr, int gelu) {
    int nwg = (Nr / 128) * MG;
    gemm_strip2<<<nwg, 256, 0, stream>>>(A, Wt, bias, Cb, MTOK, Nr, Kr, gelu);
  };

  // ---- Stage A: spatial attention ----
  gemmS(X0b, sa_qkv_t, qkvb, QKVb, QKVD, DD, 0);
  spatial_attn_mfma<<<dim3(B_ * T_, HH), 256, 0, stream>>>(QKVb, maskf, ATTb);
  gemmS(ATTb, sa_wo_t, sa_bo, PRJ, DD, DD, 0);
  add_ln<<<MTOK, 64, 0, stream>>>(x0, PRJ, sa_lw, sa_lb, R4, X1b);   // x1: R4 + X1b

  // ---- Stage B: temporal attention ----
  gemmS(X1b, ta_qkv_t, qkvb + 768, QKVb, QKVD, DD, 0);
  {
    int total = B_ * NN * HH * T_;
    temporal_attn<<<(total + 255) / 256, 256, 0, stream>>>(QKVb, ATTb);
  }
  gemmS(ATTb, ta_wo_t, ta_bo, PRJ, DD, DD, 0);
  add_ln<<<MTOK, 64, 0, stream>>>(R4, PRJ, ta_lw, ta_lb, R0, X0b);   // x2: R0 + X0b

  // ---- Stage C: FFN ----
  gemmS(X0b, f_w1_t, f_b1, HIDb, FFD, DD, 1);                        // GELU, bf16 hidden
  gemmS(HIDb, f_w2_t, f_b2, PRJ, DD, FFD, 0);                        // K=1024
  add_ln<<<MTOK, 64, 0, stream>>>(R0, PRJ, f_lw, f_lb, out, nullptr);
}